// Round 2
// baseline (369.622 us; speedup 1.0000x reference)
//
#include <hip/hip_runtime.h>
#include <hip/hip_bf16.h>
#include <hip/hip_cooperative_groups.h>

namespace cg = cooperative_groups;

typedef __bf16 bf16_t;
typedef __bf16 bf16x4 __attribute__((ext_vector_type(4)));
typedef __bf16 bf16x8 __attribute__((ext_vector_type(8)));
typedef float f32x4 __attribute__((ext_vector_type(4)));

#define NTOK 49152   // s*h*w = 3*128*128 tokens per batch
#define CDIM 128
#define CHUNKS 128   // split-K chunks for the Gram
#define KT 384       // tokens per chunk
#define STEPS 12     // KT/32

__device__ inline f32x4 mfma16(bf16x8 a, bf16x8 b, f32x4 c) {
  return __builtin_amdgcn_mfma_f32_16x16x32_bf16(a, b, c, 0, 0, 0);
}

// Raw barrier: lgkmcnt(0) only (ds_writes visible), NO vmcnt drain -> the
// prefetch global loads stay in flight across the barrier.
#define BARRIER() do { asm volatile("s_waitcnt lgkmcnt(0)" ::: "memory"); \
    __builtin_amdgcn_s_barrier(); } while (0)

#define STAGE_LOAD(st, step)                               \
  {                                                        \
    const float* p_ = gsrc + (step) * 32;                  \
    st[0] = *(const f32x4*)(p_ + 0);                       \
    st[1] = *(const f32x4*)(p_ + 4);                       \
    st[2] = *(const f32x4*)(p_ + 8);                       \
    st[3] = *(const f32x4*)(p_ + 12);                      \
  }
#define CVT4(v) (bf16x4){(bf16_t)(v)[0], (bf16_t)(v)[1], (bf16_t)(v)[2], (bf16_t)(v)[3]}
#define STAGE_WRITE(st, buf)                               \
  {                                                        \
    bf16_t* t_ = &tile[buf][0];                            \
    *(bf16x4*)&t_[cg0 * 8 + 0] = CVT4(st[0]);              \
    *(bf16x4*)&t_[cg0 * 8 + 4] = CVT4(st[1]);              \
    *(bf16x4*)&t_[cg1 * 8 + 0] = CVT4(st[2]);              \
    *(bf16x4*)&t_[cg1 * 8 + 4] = CVT4(st[3]);              \
  }
#define MFMA_PHASE(buf)                                                     \
  {                                                                         \
    bf16x8 frag[8];                                                         \
    _Pragma("unroll")                                                       \
    for (int g = 0; g < 8; ++g)                                             \
      frag[g] = *(const bf16x8*)&tile[buf][(g * 64 + lane) * 8];            \
    bf16x8 a0, a1;                                                          \
    if (wave == 0)      { a0 = frag[0]; a1 = frag[1]; }                     \
    else if (wave == 1) { a0 = frag[2]; a1 = frag[3]; }                     \
    else if (wave == 2) { a0 = frag[4]; a1 = frag[5]; }                     \
    else                { a0 = frag[6]; a1 = frag[7]; }                     \
    _Pragma("unroll")                                                       \
    for (int j = 0; j < 8; ++j) {                                           \
      acc[0][j] = mfma16(a0, frag[j], acc[0][j]);                           \
      acc[1][j] = mfma16(a1, frag[j], acc[1][j]);                           \
    }                                                                       \
  }

// ===========================================================================
// Fused single-dispatch pipeline. grid 256 x 256, cooperative (1 block/CU,
// co-residency guaranteed by hipLaunchCooperativeKernel). 6 grid syncs
// replace 6 inter-kernel dispatch boundaries (~15 us each -> ~3-5 us each).
// Phase bodies are the verified round-1 kernels, verbatim.
// ===========================================================================
__global__ __launch_bounds__(256) void fused_all(
    const float* x, const float* Wq, const float* Wk, const float* Wv,
    const float* Wp, const float* bp, const float* resc,
    float* S, float* Tm, float* attn, bf16_t* Phi, float* out) {
  cg::grid_group grid = cg::this_grid();
  const int blk = blockIdx.x;
  const int tid = threadIdx.x, wave = tid >> 6, lane = tid & 63;
  const int r = lane & 15, quad = lane >> 4;
  float* part  = out;                    // 16 MB scratch, consumed in phase 1a
  float* part2 = out + (16777216 / 4);   //  1 MB scratch at +16 MB

  __shared__ __align__(16) char smem[64 * 68 * 4];  // 17408 B union

  // ---- phase 0: Gram split-K partials (k1) ----
  {
    bf16_t (*tile)[128 * 32] = (bf16_t (*)[128 * 32])smem;
    const int b = blk >> 7, chunk = blk & 127;
    const float* Xb = x + (size_t)b * CDIM * NTOK;
    const int sch = tid >> 1, shalf = tid & 1;
    const float* gsrc = Xb + (size_t)sch * NTOK + chunk * KT + shalf * 16;
    const int c16base = ((sch >> 4) << 6) + (sch & 15);
    const int cg0 = c16base + ((shalf * 2) << 4);
    const int cg1 = c16base + ((shalf * 2 + 1) << 4);

    f32x4 stA[4], stB[4];
    f32x4 acc[2][8];
#pragma unroll
    for (int t = 0; t < 2; ++t)
#pragma unroll
      for (int j = 0; j < 8; ++j) acc[t][j] = (f32x4){0.f, 0.f, 0.f, 0.f};

    STAGE_LOAD(stA, 0);
    STAGE_WRITE(stA, 0);
    STAGE_LOAD(stB, 1);
    BARRIER();

    for (int kk = 0; kk < STEPS; kk += 2) {
      if (kk + 2 < STEPS) STAGE_LOAD(stA, kk + 2);
      STAGE_WRITE(stB, 1);
      MFMA_PHASE(0);
      BARRIER();
      if (kk + 3 < STEPS) STAGE_LOAD(stB, kk + 3);
      if (kk + 2 < STEPS) STAGE_WRITE(stA, 0);
      MFMA_PHASE(1);
      BARRIER();
    }

    // Fragment-order dump: f32x4 index = (t*8+j)*256 + tid  (decoded phase 1b)
    float* pb = part + ((size_t)(b * CHUNKS + chunk) << 14);
#pragma unroll
    for (int t = 0; t < 2; ++t)
#pragma unroll
      for (int j = 0; j < 8; ++j)
        *(f32x4*)&pb[((((t * 8 + j) << 8) + tid) << 2)] = acc[t][j];
  }
  grid.sync();

  // ---- phase 1a: reduce 128 chunks -> 8 slice-partials (k2a) ----
  {
    const int gid = blk * 256 + tid;
    const int e4 = gid & 4095, sl = (gid >> 12) & 7, b = gid >> 15;
    const float* p = part + ((size_t)(b * CHUNKS + sl * 16) << 14) + e4 * 4;
    f32x4 s0 = (f32x4){0.f, 0.f, 0.f, 0.f}, s1 = (f32x4){0.f, 0.f, 0.f, 0.f};
#pragma unroll 4
    for (int i = 0; i < 16; i += 2) {
      s0 += *(const f32x4*)(p + ((size_t)i << 14));
      s1 += *(const f32x4*)(p + ((size_t)(i + 1) << 14));
    }
    f32x4 s = s0 + s1;
    *(f32x4*)(part2 + ((size_t)(b * 8 + sl) << 14) + e4 * 4) = s;
  }
  grid.sync();

  // ---- phase 1b: sum 8 slices + un-permute -> S (k2b) ----
  if (blk < 32) {
    const int gid = blk * 256 + tid;
    const int g4 = gid & 4095, b = gid >> 12;
    f32x4 s = (f32x4){0.f, 0.f, 0.f, 0.f};
#pragma unroll
    for (int sl = 0; sl < 8; ++sl)
      s += *(const f32x4*)(part2 + ((size_t)(b * 8 + sl) << 14) + g4 * 4);
    const int tj = g4 >> 8, t = tj >> 3, j = tj & 7;
    const int tid2 = g4 & 255, w2 = tid2 >> 6, q2 = (tid2 >> 4) & 3, r2 = tid2 & 15;
    const int row0 = w2 * 32 + t * 16 + q2 * 4, col = j * 16 + r2;
    float* Sb = S + ((size_t)b << 14);
#pragma unroll
    for (int reg = 0; reg < 4; ++reg) Sb[(row0 + reg) * 128 + col] = s[reg];
  }
  grid.sync();

  // ---- phase 2: Tm[t][i][j] = sum_c W_t[i][c] S_b[j][c] (k3_t) ----
  {
    const int idx = blk * 256 + tid;
    const int j = idx & 127, i = (idx >> 7) & 127, t = (idx >> 14) & 1, b = idx >> 15;
    const f32x4* w4 = (const f32x4*)((t ? Wq : Wk) + i * 128);
    const f32x4* s4 = (const f32x4*)(S + (b << 14) + j * 128);
    float s = 0.f;
#pragma unroll 8
    for (int q = 0; q < 32; ++q) {
      const f32x4 a = w4[q], v = s4[q];
      s += a[0] * v[0] + a[1] * v[1] + a[2] * v[2] + a[3] * v[3];
    }
    Tm[idx] = s;
  }
  grid.sync();

  // ---- phase 3: norms + softmax -> attn (k3_attn), blocks 0..15 ----
  if (blk < 16) {
    const int b = blk >> 3, h = blk & 7;
    const int d = tid >> 4, e = tid & 15;
    const float* Tk = Tm + (size_t)(b * 2 + 0) * 16384;
    const float* Tq = Tm + (size_t)(b * 2 + 1) * 16384;
    const float* tkrow = Tk + (h * 16 + d) * 128;
    const float* wqrow = Wq + (h * 16 + e) * 128;
    float g = 0.f;
#pragma unroll 4
    for (int c = 0; c < 128; ++c) g += tkrow[c] * wqrow[c];

    float* sqk = (float*)smem;
    float* sqq = sqk + 16;
    if (e == 0) {
      const float* wkrow = Wk + (h * 16 + d) * 128;
      float s = 0.f;
      for (int c = 0; c < 128; ++c) s += tkrow[c] * wkrow[c];
      sqk[d] = s;
    }
    if (d == 0) {
      const float* tqrow = Tq + (h * 16 + e) * 128;
      float s = 0.f;
      for (int c = 0; c < 128; ++c) s += tqrow[c] * wqrow[c];
      sqq[e] = s;
    }
    __syncthreads();

    const float nk = fmaxf(sqrtf(fmaxf(sqk[d], 0.f)), 1e-12f);
    const float nq = fmaxf(sqrtf(fmaxf(sqq[e], 0.f)), 1e-12f);
    float pre = g / (nk * nq) * resc[h];
    float mx = pre;
#pragma unroll
    for (int m = 1; m < 16; m <<= 1) mx = fmaxf(mx, __shfl_xor(mx, m, 64));
    const float p = expf(pre - mx);
    float sum = p;
#pragma unroll
    for (int m = 1; m < 16; m <<= 1) sum += __shfl_xor(sum, m, 64);
    attn[blk * 256 + tid] = p / sum;
  }
  grid.sync();

  // ---- phase 4: Phi = Wp * blockdiag(attn) * Wv (k3_p) ----
  {
    const int b = blk >> 7, rrow = blk & 127;
    float* M = (float*)smem;
    if (tid < 128) {
      const int h = tid >> 4, e = tid & 15;
      const float* A = attn + (size_t)(b * 8 + h) * 256;
      const float* wp = Wp + rrow * 128 + h * 16;
      float m = 0.f;
#pragma unroll
      for (int dd = 0; dd < 16; ++dd) m += wp[dd] * A[dd * 16 + e];
      M[tid] = m;
    }
    __syncthreads();
    if (tid < 128) {
      const int c = tid;
      float p = 0.f;
#pragma unroll 4
      for (int j = 0; j < 128; ++j) p += M[j] * Wv[j * 128 + c];
      Phi[((size_t)b << 14) + rrow * 128 + c] = (bf16_t)p;
    }
  }
  grid.sync();

  // ---- phase 5: out = Phi_b X_b + bp (k4), grid-strided 6 tiles/block ----
#pragma unroll 1
  for (int it = 0; it < 6; ++it) {
    __syncthreads();  // previous iteration's tbuf reads done before restage
    const int tgi = it * 256 + blk;
    const int b = tgi / 768, tg = tgi % 768;
    const float* Xb = x + (size_t)b * CDIM * NTOK;
    const bf16_t* Ph = Phi + ((size_t)b << 14);
    float* Ob = out + (size_t)b * CDIM * NTOK;
    const int tok0 = tg * 64;
    bf16_t* tile4 = (bf16_t*)smem;
    float* tbuf = (float*)smem;

    {
      const int sch = tid >> 1, shalf = tid & 1;
      const float* p = Xb + (size_t)sch * NTOK + tok0 + shalf * 32;
      f32x4 st[8];
#pragma unroll
      for (int q = 0; q < 8; ++q) st[q] = *(const f32x4*)(p + q * 4);
      const int chunk_hi = ((sch >> 5) << 8) + (((sch >> 3) & 3) << 4);
      const int ei = sch & 7;
#pragma unroll
      for (int j = 0; j < 32; ++j) {
        const int tok = shalf * 32 + j;
        const int chunk = chunk_hi + ((tok >> 4) << 6) + (tok & 15);
        tile4[chunk * 8 + ei] = (bf16_t)st[j >> 2][j & 3];
      }
    }
    __syncthreads();

    f32x4 acc4[8];
#pragma unroll
    for (int m = 0; m < 8; ++m) acc4[m] = (f32x4){0.f, 0.f, 0.f, 0.f};
#pragma unroll
    for (int step = 0; step < 4; ++step) {
      const bf16x8 bfr = *(const bf16x8*)&tile4[(step * 256 + wave * 64 + lane) * 8];
#pragma unroll
      for (int m = 0; m < 8; ++m) {
        const bf16x8 ah = *(const bf16x8*)(Ph + (16 * m + r) * 128 + step * 32 + quad * 8);
        acc4[m] = mfma16(ah, bfr, acc4[m]);
      }
    }
    __syncthreads();  // all waves done reading tile4 before reuse as tbuf

#pragma unroll
    for (int half = 0; half < 2; ++half) {
#pragma unroll
      for (int mm = 0; mm < 4; ++mm) {
#pragma unroll
        for (int reg = 0; reg < 4; ++reg)
          tbuf[(mm * 16 + quad * 4 + reg) * 68 + wave * 16 + r] = acc4[half * 4 + mm][reg];
      }
      __syncthreads();
#pragma unroll
      for (int rep = 0; rep < 4; ++rep) {
        const int idx = rep * 256 + tid, rloc = idx >> 4, gg = idx & 15;
        f32x4 v = *(const f32x4*)&tbuf[rloc * 68 + gg * 4];
        const int row = half * 64 + rloc;
        const float bb = bp[row];
        v[0] += bb; v[1] += bb; v[2] += bb; v[3] += bb;
        *(f32x4*)&Ob[(size_t)row * NTOK + tok0 + gg * 4] = v;
      }
      if (half == 0) __syncthreads();
    }
  }
}

// ===========================================================================
// Fallback path: the verified round-1 7-kernel pipeline (used only if the
// cooperative launch is rejected at runtime).
// ===========================================================================
__global__ __launch_bounds__(256) void k1_gram(const float* __restrict__ x,
                                               float* __restrict__ part) {
  const int blk = blockIdx.x;
  const int b = blk >> 7, chunk = blk & 127;
  const float* Xb = x + (size_t)b * CDIM * NTOK;
  const int tid = threadIdx.x, wave = tid >> 6, lane = tid & 63;

  __shared__ __align__(16) bf16_t tile[2][128 * 32];

  const int sch = tid >> 1, shalf = tid & 1;
  const float* gsrc = Xb + (size_t)sch * NTOK + chunk * KT + shalf * 16;
  const int c16base = ((sch >> 4) << 6) + (sch & 15);
  const int cg0 = c16base + ((shalf * 2) << 4);
  const int cg1 = c16base + ((shalf * 2 + 1) << 4);

  f32x4 stA[4], stB[4];
  f32x4 acc[2][8];
#pragma unroll
  for (int t = 0; t < 2; ++t)
#pragma unroll
    for (int j = 0; j < 8; ++j) acc[t][j] = (f32x4){0.f, 0.f, 0.f, 0.f};

  STAGE_LOAD(stA, 0);
  STAGE_WRITE(stA, 0);
  STAGE_LOAD(stB, 1);
  BARRIER();

  for (int kk = 0; kk < STEPS; kk += 2) {
    if (kk + 2 < STEPS) STAGE_LOAD(stA, kk + 2);
    STAGE_WRITE(stB, 1);
    MFMA_PHASE(0);
    BARRIER();
    if (kk + 3 < STEPS) STAGE_LOAD(stB, kk + 3);
    if (kk + 2 < STEPS) STAGE_WRITE(stA, 0);
    MFMA_PHASE(1);
    BARRIER();
  }

  float* pb = part + ((size_t)(b * CHUNKS + chunk) << 14);
#pragma unroll
  for (int t = 0; t < 2; ++t)
#pragma unroll
    for (int j = 0; j < 8; ++j)
      *(f32x4*)&pb[((((t * 8 + j) << 8) + tid) << 2)] = acc[t][j];
}

__global__ __launch_bounds__(256) void k2a_reduce(const float* __restrict__ part,
                                                  float* __restrict__ part2) {
  const int gid = blockIdx.x * 256 + threadIdx.x;
  const int e4 = gid & 4095, sl = (gid >> 12) & 7, b = gid >> 15;
  const float* p = part + ((size_t)(b * CHUNKS + sl * 16) << 14) + e4 * 4;
  f32x4 s = (f32x4){0.f, 0.f, 0.f, 0.f};
#pragma unroll 8
  for (int i = 0; i < 16; ++i) s += *(const f32x4*)(p + ((size_t)i << 14));
  *(f32x4*)(part2 + ((size_t)(b * 8 + sl) << 14) + e4 * 4) = s;
}

__global__ __launch_bounds__(256) void k2b_reduce(const float* __restrict__ part2,
                                                  float* __restrict__ S) {
  const int gid = blockIdx.x * 256 + threadIdx.x;
  const int g4 = gid & 4095, b = gid >> 12;
  f32x4 s = (f32x4){0.f, 0.f, 0.f, 0.f};
#pragma unroll
  for (int sl = 0; sl < 8; ++sl)
    s += *(const f32x4*)(part2 + ((size_t)(b * 8 + sl) << 14) + g4 * 4);
  const int tj = g4 >> 8, t = tj >> 3, j = tj & 7;
  const int tid2 = g4 & 255, wave = tid2 >> 6, quad = (tid2 >> 4) & 3, r = tid2 & 15;
  const int row0 = wave * 32 + t * 16 + quad * 4, col = j * 16 + r;
  float* Sb = S + ((size_t)b << 14);
#pragma unroll
  for (int reg = 0; reg < 4; ++reg) Sb[(row0 + reg) * 128 + col] = s[reg];
}

__global__ __launch_bounds__(256) void k3_t(const float* __restrict__ S,
                                            const float* __restrict__ Wk,
                                            const float* __restrict__ Wq,
                                            float* __restrict__ Tm) {
  const int idx = blockIdx.x * 256 + threadIdx.x;
  const int j = idx & 127, i = (idx >> 7) & 127, t = (idx >> 14) & 1, b = idx >> 15;
  const f32x4* w4 = (const f32x4*)((t ? Wq : Wk) + i * 128);
  const f32x4* s4 = (const f32x4*)(S + (b << 14) + j * 128);
  float s = 0.f;
#pragma unroll 8
  for (int q = 0; q < 32; ++q) {
    const f32x4 a = w4[q], v = s4[q];
    s += a[0] * v[0] + a[1] * v[1] + a[2] * v[2] + a[3] * v[3];
  }
  Tm[idx] = s;
}

__global__ __launch_bounds__(256) void k3_attn(const float* __restrict__ Tm,
                                               const float* __restrict__ Wk,
                                               const float* __restrict__ Wq,
                                               const float* __restrict__ resc,
                                               float* __restrict__ attn) {
  const int blk = blockIdx.x;
  const int b = blk >> 3, h = blk & 7;
  const int tid = threadIdx.x, d = tid >> 4, e = tid & 15;
  const float* Tk = Tm + (size_t)(b * 2 + 0) * 16384;
  const float* Tq = Tm + (size_t)(b * 2 + 1) * 16384;

  const float* tkrow = Tk + (h * 16 + d) * 128;
  const float* wqrow = Wq + (h * 16 + e) * 128;
  float g = 0.f;
#pragma unroll 4
  for (int c = 0; c < 128; ++c) g += tkrow[c] * wqrow[c];

  __shared__ float sqk[16], sqq[16];
  if (e == 0) {
    const float* wkrow = Wk + (h * 16 + d) * 128;
    float s = 0.f;
    for (int c = 0; c < 128; ++c) s += tkrow[c] * wkrow[c];
    sqk[d] = s;
  }
  if (d == 0) {
    const float* tqrow = Tq + (h * 16 + e) * 128;
    float s = 0.f;
    for (int c = 0; c < 128; ++c) s += tqrow[c] * wqrow[c];
    sqq[e] = s;
  }
  __syncthreads();

  const float nk = fmaxf(sqrtf(fmaxf(sqk[d], 0.f)), 1e-12f);
  const float nq = fmaxf(sqrtf(fmaxf(sqq[e], 0.f)), 1e-12f);
  float pre = g / (nk * nq) * resc[h];

  float mx = pre;
#pragma unroll
  for (int m = 1; m < 16; m <<= 1) mx = fmaxf(mx, __shfl_xor(mx, m, 64));
  const float p = expf(pre - mx);
  float sum = p;
#pragma unroll
  for (int m = 1; m < 16; m <<= 1) sum += __shfl_xor(sum, m, 64);
  attn[blk * 256 + tid] = p / sum;
}

__global__ __launch_bounds__(256) void k3_p(const float* __restrict__ attn,
                                            const float* __restrict__ Wp,
                                            const float* __restrict__ Wv,
                                            bf16_t* __restrict__ Phi) {
  const int blk = blockIdx.x;
  const int b = blk >> 7, rrow = blk & 127;
  const int tid = threadIdx.x;
  __shared__ float M[128];
  if (tid < 128) {
    const int h = tid >> 4, e = tid & 15;
    const float* A = attn + (size_t)(b * 8 + h) * 256;
    const float* wp = Wp + rrow * 128 + h * 16;
    float m = 0.f;
#pragma unroll
    for (int d = 0; d < 16; ++d) m += wp[d] * A[d * 16 + e];
    M[tid] = m;
  }
  __syncthreads();
  if (tid < 128) {
    const int c = tid;
    float p = 0.f;
#pragma unroll 4
    for (int j = 0; j < 128; ++j) p += M[j] * Wv[j * 128 + c];
    Phi[((size_t)b << 14) + rrow * 128 + c] = (bf16_t)p;
  }
}

__global__ __launch_bounds__(256) void k4_out(const float* __restrict__ x,
                                              const bf16_t* __restrict__ Phi,
                                              const float* __restrict__ bp,
                                              float* __restrict__ out) {
  const int blk = blockIdx.x;
  const int b = blk / 768, tg = blk % 768;
  const float* Xb = x + (size_t)b * CDIM * NTOK;
  const bf16_t* Ph = Phi + ((size_t)b << 14);
  float* Ob = out + (size_t)b * CDIM * NTOK;
  const int tid = threadIdx.x, wave = tid >> 6, lane = tid & 63;
  const int r = lane & 15, quad = lane >> 4;
  const int tok0 = tg * 64;

  __shared__ __align__(16) char smem[64 * 68 * 4];
  bf16_t* tile = (bf16_t*)smem;
  float* tbuf = (float*)smem;

  {
    const int sch = tid >> 1, shalf = tid & 1;
    const float* p = Xb + (size_t)sch * NTOK + tok0 + shalf * 32;
    f32x4 st[8];
#pragma unroll
    for (int q = 0; q < 8; ++q) st[q] = *(const f32x4*)(p + q * 4);
    const int chunk_hi = ((sch >> 5) << 8) + (((sch >> 3) & 3) << 4);
    const int ei = sch & 7;
#pragma unroll
    for (int j = 0; j < 32; ++j) {
      const int tok = shalf * 32 + j;
      const int chunk = chunk_hi + ((tok >> 4) << 6) + (tok & 15);
      tile[chunk * 8 + ei] = (bf16_t)st[j >> 2][j & 3];
    }
  }
  __syncthreads();

  f32x4 acc[8];
#pragma unroll
  for (int m = 0; m < 8; ++m) acc[m] = (f32x4){0.f, 0.f, 0.f, 0.f};

#pragma unroll
  for (int step = 0; step < 4; ++step) {
    const bf16x8 bfr = *(const bf16x8*)&tile[(step * 256 + wave * 64 + lane) * 8];
#pragma unroll
    for (int m = 0; m < 8; ++m) {
      const bf16x8 ah = *(const bf16x8*)(Ph + (16 * m + r) * 128 + step * 32 + quad * 8);
      acc[m] = mfma16(ah, bfr, acc[m]);
    }
  }

  __syncthreads();
#pragma unroll
  for (int half = 0; half < 2; ++half) {
#pragma unroll
    for (int mm = 0; mm < 4; ++mm) {
#pragma unroll
      for (int reg = 0; reg < 4; ++reg)
        tbuf[(mm * 16 + quad * 4 + reg) * 68 + wave * 16 + r] = acc[half * 4 + mm][reg];
    }
    __syncthreads();
#pragma unroll
    for (int rep = 0; rep < 4; ++rep) {
      const int idx = rep * 256 + tid, rloc = idx >> 4, g = idx & 15;
      f32x4 v = *(const f32x4*)&tbuf[rloc * 68 + g * 4];
      const int row = half * 64 + rloc;
      const float bb = bp[row];
      v[0] += bb; v[1] += bb; v[2] += bb; v[3] += bb;
      *(f32x4*)&Ob[(size_t)row * NTOK + tok0 + g * 4] = v;
    }
    if (half == 0) __syncthreads();
  }
}

extern "C" void kernel_launch(void* const* d_in, const int* in_sizes, int n_in,
                              void* d_out, int out_size, void* d_ws, size_t ws_size,
                              hipStream_t stream) {
  const float* x    = (const float*)d_in[0];
  const float* Wq   = (const float*)d_in[1];
  const float* Wk   = (const float*)d_in[2];
  const float* Wv   = (const float*)d_in[3];
  const float* Wp   = (const float*)d_in[4];
  const float* bp   = (const float*)d_in[5];
  const float* resc = (const float*)d_in[6];
  float* out = (float*)d_out;

  // Small scratch in d_ws (<= 442 KB used).
  char* ws = (char*)d_ws;
  float*  S    = (float*)(ws + 0);        // 131072 B
  float*  Tm   = (float*)(ws + 131072);   // 262144 B
  float*  attn = (float*)(ws + 393216);   //  16384 B
  bf16_t* Phi  = (bf16_t*)(ws + 409600);  //  65536 B
  // Big scratch inside d_out: partials 16 MB + part2 1 MB, consumed before
  // the final phase overwrites d_out with the real output.
  float* part  = (float*)d_out;
  float* part2 = (float*)((char*)d_out + 16777216);

  // Single cooperative dispatch (256 blocks = 1/CU, co-residency guaranteed).
  const float *a0 = x, *a1 = Wq, *a2 = Wk, *a3 = Wv, *a4 = Wp, *a5 = bp, *a6 = resc;
  float *a7 = S, *a8 = Tm, *a9 = attn;
  bf16_t* a10 = Phi;
  float* a11 = out;
  void* args[12] = {&a0, &a1, &a2, &a3, &a4, &a5, &a6, &a7, &a8, &a9, &a10, &a11};
  hipError_t err = hipLaunchCooperativeKernel((const void*)fused_all, dim3(256),
                                              dim3(256), args, 0, stream);
  if (err != hipSuccess) {
    (void)hipGetLastError();  // clear sticky error; fall back to 7-dispatch path
    k1_gram<<<2 * CHUNKS, 256, 0, stream>>>(x, part);
    k2a_reduce<<<256, 256, 0, stream>>>(part, part2);
    k2b_reduce<<<32, 256, 0, stream>>>(part2, S);
    k3_t<<<256, 256, 0, stream>>>(S, Wk, Wq, Tm);
    k3_attn<<<16, 256, 0, stream>>>(Tm, Wk, Wq, resc, attn);
    k3_p<<<256, 256, 0, stream>>>(attn, Wp, Wv, Phi);
    k4_out<<<1536, 256, 0, stream>>>(x, Phi, bp, out);
  }
}

// Round 3
// 226.880 us; speedup vs baseline: 1.6291x; 1.6291x over previous
//
#include <hip/hip_runtime.h>
#include <hip/hip_bf16.h>

typedef __bf16 bf16_t;
typedef __bf16 bf16x4 __attribute__((ext_vector_type(4)));
typedef __bf16 bf16x8 __attribute__((ext_vector_type(8)));
typedef float f32x4 __attribute__((ext_vector_type(4)));

#define NTOK 49152   // s*h*w = 3*128*128 tokens per batch
#define CDIM 128
#define CHUNKS 128   // split-K chunks for the Gram (grid = 256, 1 block/CU)
#define KT 384       // tokens per chunk
#define STEPS 12     // KT/32

__device__ inline f32x4 mfma16(bf16x8 a, bf16x8 b, f32x4 c) {
  return __builtin_amdgcn_mfma_f32_16x16x32_bf16(a, b, c, 0, 0, 0);
}

// Raw barrier: lgkmcnt(0) only (ds_writes visible), NO vmcnt drain -> the
// prefetch global loads stay in flight across the barrier.
#define BARRIER() do { asm volatile("s_waitcnt lgkmcnt(0)" ::: "memory"); \
    __builtin_amdgcn_s_barrier(); } while (0)

#define STAGE_LOAD(st, step)                               \
  {                                                        \
    const float* p_ = gsrc + (step) * 32;                  \
    st[0] = *(const f32x4*)(p_ + 0);                       \
    st[1] = *(const f32x4*)(p_ + 4);                       \
    st[2] = *(const f32x4*)(p_ + 8);                       \
    st[3] = *(const f32x4*)(p_ + 12);                      \
  }
#define CVT4(v) (bf16x4){(bf16_t)(v)[0], (bf16_t)(v)[1], (bf16_t)(v)[2], (bf16_t)(v)[3]}
#define STAGE_WRITE(st, buf)                               \
  {                                                        \
    bf16_t* t_ = &tile[buf][0];                            \
    *(bf16x4*)&t_[cg0 * 8 + 0] = CVT4(st[0]);              \
    *(bf16x4*)&t_[cg0 * 8 + 4] = CVT4(st[1]);              \
    *(bf16x4*)&t_[cg1 * 8 + 0] = CVT4(st[2]);              \
    *(bf16x4*)&t_[cg1 * 8 + 4] = CVT4(st[3]);              \
  }
#define MFMA_PHASE(buf)                                                     \
  {                                                                         \
    bf16x8 frag[8];                                                         \
    _Pragma("unroll")                                                       \
    for (int g = 0; g < 8; ++g)                                             \
      frag[g] = *(const bf16x8*)&tile[buf][(g * 64 + lane) * 8];            \
    bf16x8 a0, a1;                                                          \
    if (wave == 0)      { a0 = frag[0]; a1 = frag[1]; }                     \
    else if (wave == 1) { a0 = frag[2]; a1 = frag[3]; }                     \
    else if (wave == 2) { a0 = frag[4]; a1 = frag[5]; }                     \
    else                { a0 = frag[6]; a1 = frag[7]; }                     \
    _Pragma("unroll")                                                       \
    for (int j = 0; j < 8; ++j) {                                           \
      acc[0][j] = mfma16(a0, frag[j], acc[0][j]);                           \
      acc[1][j] = mfma16(a1, frag[j], acc[1][j]);                           \
    }                                                                       \
  }

// ---------------------------------------------------------------------------
// D1: Gram split-K (round-1 proven body) + EMBEDDED group reduction.
// After the frag-order partial dump, each block release-fences and bumps its
// 16-chunk group counter; the 16th (last) arrival acquire-fences and reduces
// the group's 16 partials -> part2 (8 slices per batch, frag order).
// No spinning: the last arrival does the work, so no residency assumption.
// ---------------------------------------------------------------------------
__global__ __launch_bounds__(256) void k1_gramred(const float* __restrict__ x,
                                                  float* __restrict__ part,
                                                  float* __restrict__ part2,
                                                  int* __restrict__ cnt) {
  const int blk = blockIdx.x;
  const int b = blk >> 7, chunk = blk & 127;
  const float* Xb = x + (size_t)b * CDIM * NTOK;
  const int tid = threadIdx.x, wave = tid >> 6, lane = tid & 63;

  __shared__ __align__(16) bf16_t tile[2][128 * 32];

  const int sch = tid >> 1, shalf = tid & 1;
  const float* gsrc = Xb + (size_t)sch * NTOK + chunk * KT + shalf * 16;
  const int c16base = ((sch >> 4) << 6) + (sch & 15);
  const int cg0 = c16base + ((shalf * 2) << 4);
  const int cg1 = c16base + ((shalf * 2 + 1) << 4);

  f32x4 stA[4], stB[4];
  f32x4 acc[2][8];
#pragma unroll
  for (int t = 0; t < 2; ++t)
#pragma unroll
    for (int j = 0; j < 8; ++j) acc[t][j] = (f32x4){0.f, 0.f, 0.f, 0.f};

  STAGE_LOAD(stA, 0);
  STAGE_WRITE(stA, 0);
  STAGE_LOAD(stB, 1);
  BARRIER();

  for (int kk = 0; kk < STEPS; kk += 2) {
    if (kk + 2 < STEPS) STAGE_LOAD(stA, kk + 2);
    STAGE_WRITE(stB, 1);
    MFMA_PHASE(0);
    BARRIER();
    if (kk + 3 < STEPS) STAGE_LOAD(stB, kk + 3);
    if (kk + 2 < STEPS) STAGE_WRITE(stA, 0);
    MFMA_PHASE(1);
    BARRIER();
  }

  // Fragment-order dump: f32x4 index = (t*8+j)*256 + tid (decoded in kmid).
  float* pb = part + ((size_t)(b * CHUNKS + chunk) << 14);
#pragma unroll
  for (int t = 0; t < 2; ++t)
#pragma unroll
    for (int j = 0; j < 8; ++j)
      *(f32x4*)&pb[((((t * 8 + j) << 8) + tid) << 2)] = acc[t][j];

  // ---- embedded k2a: last block of each 16-chunk group reduces ----
  __threadfence();            // release: publish this block's partial (wbl2)
  __syncthreads();            // all lanes fenced before the flag
  __shared__ int lastf;
  if (tid == 0)
    lastf = (atomicAdd(&cnt[b * 8 + (chunk >> 4)], 1) == 15) ? 1 : 0;
  __syncthreads();
  if (lastf) {
    __threadfence();          // acquire: invalidate stale L1/L2 before reads
    const int g = chunk >> 4;
    const float* src0 = part + ((size_t)(b * CHUNKS + g * 16) << 14);
    float* dst = part2 + ((size_t)(b * 8 + g) << 14);
#pragma unroll 1
    for (int k = 0; k < 16; ++k) {
      const int idx4 = k * 256 + tid;
      f32x4 s = (f32x4){0.f, 0.f, 0.f, 0.f};
#pragma unroll
      for (int i = 0; i < 16; ++i)
        s += *(const f32x4*)(src0 + (((size_t)i) << 14) + idx4 * 4);
      *(f32x4*)(dst + idx4 * 4) = s;
    }
  }
}

// ---------------------------------------------------------------------------
// D2: kmid -- the entire middle in one dispatch. grid 16 = (b, h).
// Phase A: sum 8 frag-order slices -> S (un-permuted) in LDS; stage W rows.
// Phase B: Tk = Wk_h S, Tq = Wq_h S (S symmetric), register-blocked.
// Phase C: G, diagonals, softmax (verbatim k3_attn math) -> A in LDS.
// Phase M: M-columns for this head -> Mbuf (global ws).
// Spin (bounded; 16 blocks <= 256 CUs, all resident) until the batch's 8
// heads published M, then each block computes its 16 Phi columns (bf16).
// ---------------------------------------------------------------------------
__global__ __launch_bounds__(256) void kmid(const float* __restrict__ part2,
                                            const float* __restrict__ Wk,
                                            const float* __restrict__ Wq,
                                            const float* __restrict__ Wp,
                                            const float* __restrict__ Wv,
                                            const float* __restrict__ resc,
                                            float* __restrict__ Mbuf,
                                            bf16_t* __restrict__ Phi,
                                            int* __restrict__ cntM) {
  const int blk = blockIdx.x;  // 16 = b*8 + h
  const int b = blk >> 3, h = blk & 7;
  const int tid = threadIdx.x;

  __shared__ float S_l[128][132];            // padded: conflict-tamed
  __shared__ float Wk_l[16][128], Wq_l[16][128];
  __shared__ float Tk_l[16][132], Tq_l[16][132];
  __shared__ float A_l[16][16];
  __shared__ float dK[16], dQ[16];

  // ---- Phase A: S-sum + un-permute; stage W head rows ----
  {
    const float* p0 = part2 + ((size_t)(b * 8) << 14);
#pragma unroll 1
    for (int k = 0; k < 16; ++k) {
      const int g4 = k * 256 + tid;
      f32x4 s = (f32x4){0.f, 0.f, 0.f, 0.f};
#pragma unroll
      for (int sl = 0; sl < 8; ++sl)
        s += *(const f32x4*)(p0 + ((size_t)sl << 14) + g4 * 4);
      const int tj = g4 >> 8, t_ = tj >> 3, j_ = tj & 7;
      const int t2 = g4 & 255, w2 = t2 >> 6, q2 = (t2 >> 4) & 3, r2 = t2 & 15;
      const int row0 = w2 * 32 + t_ * 16 + q2 * 4, col = j_ * 16 + r2;
#pragma unroll
      for (int reg = 0; reg < 4; ++reg) S_l[row0 + reg][col] = s[reg];
    }
#pragma unroll
    for (int k = 0; k < 8; ++k) {
      const int idx = k * 256 + tid;  // 0..2047
      Wk_l[idx >> 7][idx & 127] = Wk[h * 2048 + idx];
      Wq_l[idx >> 7][idx & 127] = Wq[h * 2048 + idx];
    }
  }
  __syncthreads();

  // ---- Phase B: Tk/Tq. Thread owns d in {d2, d2+8}, j in [j0, j0+4). ----
  {
    const int d2 = tid >> 5;
    const int j0 = (tid & 31) * 4;
    f32x4 aK0 = (f32x4){0.f,0.f,0.f,0.f}, aK1 = (f32x4){0.f,0.f,0.f,0.f};
    f32x4 aQ0 = (f32x4){0.f,0.f,0.f,0.f}, aQ1 = (f32x4){0.f,0.f,0.f,0.f};
#pragma unroll 1
    for (int cb = 0; cb < 4; ++cb) {
      f32x4 wk0[8], wk1[8], wq0[8], wq1[8];
#pragma unroll
      for (int q = 0; q < 8; ++q) {
        wk0[q] = *(const f32x4*)&Wk_l[d2][cb * 32 + q * 4];
        wk1[q] = *(const f32x4*)&Wk_l[d2 + 8][cb * 32 + q * 4];
        wq0[q] = *(const f32x4*)&Wq_l[d2][cb * 32 + q * 4];
        wq1[q] = *(const f32x4*)&Wq_l[d2 + 8][cb * 32 + q * 4];
      }
#pragma unroll
      for (int q = 0; q < 8; ++q) {
#pragma unroll
        for (int cc = 0; cc < 4; ++cc) {
          const int c = cb * 32 + q * 4 + cc;
          const f32x4 sv = *(const f32x4*)&S_l[c][j0];  // S[c][j] == S[j][c]
          aK0 += sv * wk0[q][cc];
          aK1 += sv * wk1[q][cc];
          aQ0 += sv * wq0[q][cc];
          aQ1 += sv * wq1[q][cc];
        }
      }
    }
    *(f32x4*)&Tk_l[d2][j0]     = aK0;
    *(f32x4*)&Tk_l[d2 + 8][j0] = aK1;
    *(f32x4*)&Tq_l[d2][j0]     = aQ0;
    *(f32x4*)&Tq_l[d2 + 8][j0] = aQ1;
  }
  __syncthreads();

  // ---- Phase C: G, diagonals, softmax -> A_l ----
  {
    const int d = tid >> 4, e = tid & 15;
    f32x4 gacc = (f32x4){0.f,0.f,0.f,0.f};
    f32x4 kacc = (f32x4){0.f,0.f,0.f,0.f};
    f32x4 qacc = (f32x4){0.f,0.f,0.f,0.f};
#pragma unroll
    for (int j4 = 0; j4 < 32; ++j4) {
      const f32x4 tk = *(const f32x4*)&Tk_l[d][j4 * 4];
      const f32x4 wq = *(const f32x4*)&Wq_l[e][j4 * 4];
      gacc += tk * wq;
      if (e == 0) kacc += tk * (*(const f32x4*)&Wk_l[d][j4 * 4]);
      if (d == 0) qacc += (*(const f32x4*)&Tq_l[e][j4 * 4]) * wq;
    }
    if (e == 0) dK[d] = kacc[0] + kacc[1] + kacc[2] + kacc[3];
    if (d == 0) dQ[e] = qacc[0] + qacc[1] + qacc[2] + qacc[3];
    __syncthreads();
    const float g = gacc[0] + gacc[1] + gacc[2] + gacc[3];
    const float nk = fmaxf(sqrtf(fmaxf(dK[d], 0.f)), 1e-12f);
    const float nq = fmaxf(sqrtf(fmaxf(dQ[e], 0.f)), 1e-12f);
    float pre = g / (nk * nq) * resc[h];
    float mx = pre;
#pragma unroll
    for (int m = 1; m < 16; m <<= 1) mx = fmaxf(mx, __shfl_xor(mx, m, 64));
    const float p = expf(pre - mx);
    float sum = p;
#pragma unroll
    for (int m = 1; m < 16; m <<= 1) sum += __shfl_xor(sum, m, 64);
    A_l[d][e] = p / sum;
  }
  __syncthreads();

  // ---- Phase M: Mbuf[b][r][h*16+e] = sum_d Wp[r][h16+d] * A[d][e] ----
  {
    const int e = tid & 15, rg = tid >> 4;  // 16 r-groups x 8 rows
#pragma unroll
    for (int k = 0; k < 8; ++k) {
      const int r = rg * 8 + k;
      const f32x4* wp4 = (const f32x4*)(Wp + r * 128 + h * 16);
      float m = 0.f;
#pragma unroll
      for (int q = 0; q < 4; ++q) {
        const f32x4 w = wp4[q];
        m += w[0] * A_l[q * 4 + 0][e] + w[1] * A_l[q * 4 + 1][e] +
             w[2] * A_l[q * 4 + 2][e] + w[3] * A_l[q * 4 + 3][e];
      }
      Mbuf[(size_t)b * 16384 + r * 128 + h * 16 + e] = m;
    }
  }

  // publish M; wait for all 8 heads of this batch (all blocks resident).
  __threadfence();
  __syncthreads();
  if (tid == 0) {
    atomicAdd(&cntM[b], 1);
    while (__hip_atomic_load(&cntM[b], __ATOMIC_RELAXED,
                             __HIP_MEMORY_SCOPE_AGENT) < 8)
      __builtin_amdgcn_s_sleep(16);
  }
  __syncthreads();
  __threadfence();  // acquire: M rows from other heads' blocks

  // ---- Phi slice: columns h*16 .. h*16+15 of Phi[b] ----
  {
    const int cc = tid & 15, rg = tid >> 4;
    const float* Mb = Mbuf + (size_t)b * 16384;
    float pacc[8] = {0.f, 0.f, 0.f, 0.f, 0.f, 0.f, 0.f, 0.f};
#pragma unroll 2
    for (int j4 = 0; j4 < 32; ++j4) {
      float wv[4];
#pragma unroll
      for (int jj = 0; jj < 4; ++jj)
        wv[jj] = Wv[(j4 * 4 + jj) * 128 + h * 16 + cc];
#pragma unroll
      for (int k = 0; k < 8; ++k) {
        const f32x4 m4 = *(const f32x4*)&Mb[(rg * 8 + k) * 128 + j4 * 4];
        pacc[k] += m4[0] * wv[0] + m4[1] * wv[1] + m4[2] * wv[2] + m4[3] * wv[3];
      }
    }
#pragma unroll
    for (int k = 0; k < 8; ++k)
      Phi[((size_t)b << 14) + (rg * 8 + k) * 128 + h * 16 + cc] = (bf16_t)pacc[k];
  }
}

// ---------------------------------------------------------------------------
// D3: out[b] = Phi_b X_b + bp (unchanged round-1 proven kernel). grid 1536.
// ---------------------------------------------------------------------------
__global__ __launch_bounds__(256) void k4_out(const float* __restrict__ x,
                                              const bf16_t* __restrict__ Phi,
                                              const float* __restrict__ bp,
                                              float* __restrict__ out) {
  const int blk = blockIdx.x;
  const int b = blk / 768, tg = blk % 768;
  const float* Xb = x + (size_t)b * CDIM * NTOK;
  const bf16_t* Ph = Phi + ((size_t)b << 14);
  float* Ob = out + (size_t)b * CDIM * NTOK;
  const int tid = threadIdx.x, wave = tid >> 6, lane = tid & 63;
  const int r = lane & 15, quad = lane >> 4;
  const int tok0 = tg * 64;

  __shared__ __align__(16) char smem[64 * 68 * 4];
  bf16_t* tile = (bf16_t*)smem;
  float* tbuf = (float*)smem;

  {
    const int sch = tid >> 1, shalf = tid & 1;
    const float* p = Xb + (size_t)sch * NTOK + tok0 + shalf * 32;
    f32x4 st[8];
#pragma unroll
    for (int q = 0; q < 8; ++q) st[q] = *(const f32x4*)(p + q * 4);
    const int chunk_hi = ((sch >> 5) << 8) + (((sch >> 3) & 3) << 4);
    const int ei = sch & 7;
#pragma unroll
    for (int j = 0; j < 32; ++j) {
      const int tok = shalf * 32 + j;
      const int chunk = chunk_hi + ((tok >> 4) << 6) + (tok & 15);
      tile[chunk * 8 + ei] = (bf16_t)st[j >> 2][j & 3];
    }
  }
  __syncthreads();

  f32x4 acc[8];
#pragma unroll
  for (int m = 0; m < 8; ++m) acc[m] = (f32x4){0.f, 0.f, 0.f, 0.f};

#pragma unroll
  for (int step = 0; step < 4; ++step) {
    const bf16x8 bfr = *(const bf16x8*)&tile[(step * 256 + wave * 64 + lane) * 8];
#pragma unroll
    for (int m = 0; m < 8; ++m) {
      const bf16x8 ah = *(const bf16x8*)(Ph + (16 * m + r) * 128 + step * 32 + quad * 8);
      acc[m] = mfma16(ah, bfr, acc[m]);
    }
  }

  __syncthreads();
#pragma unroll
  for (int half = 0; half < 2; ++half) {
#pragma unroll
    for (int mm = 0; mm < 4; ++mm) {
#pragma unroll
      for (int reg = 0; reg < 4; ++reg)
        tbuf[(mm * 16 + quad * 4 + reg) * 68 + wave * 16 + r] = acc[half * 4 + mm][reg];
    }
    __syncthreads();
#pragma unroll
    for (int rep = 0; rep < 4; ++rep) {
      const int idx = rep * 256 + tid, rloc = idx >> 4, g = idx & 15;
      f32x4 v = *(const f32x4*)&tbuf[rloc * 68 + g * 4];
      const int row = half * 64 + rloc;
      const float bb = bp[row];
      v[0] += bb; v[1] += bb; v[2] += bb; v[3] += bb;
      *(f32x4*)&Ob[(size_t)row * NTOK + tok0 + g * 4] = v;
    }
    if (half == 0) __syncthreads();
  }
}

extern "C" void kernel_launch(void* const* d_in, const int* in_sizes, int n_in,
                              void* d_out, int out_size, void* d_ws, size_t ws_size,
                              hipStream_t stream) {
  const float* x    = (const float*)d_in[0];
  const float* Wq   = (const float*)d_in[1];
  const float* Wk   = (const float*)d_in[2];
  const float* Wv   = (const float*)d_in[3];
  const float* Wp   = (const float*)d_in[4];
  const float* bp   = (const float*)d_in[5];
  const float* resc = (const float*)d_in[6];
  float* out = (float*)d_out;

  // ws layout: Mbuf f32[2*128*128] @0 (131072 B) | Phi bf16[2*128*128]
  // @131072 (65536 B) | counters @196608 (128 B: cnt[16], cntM[2]).
  char* ws = (char*)d_ws;
  float*  Mbuf = (float*)(ws + 0);
  bf16_t* Phi  = (bf16_t*)(ws + 131072);
  int*    cnt  = (int*)(ws + 196608);
  int*    cntM = cnt + 16;
  // Big scratch inside d_out (50.3 MB): part 16 MB + part2 1 MB, consumed by
  // kmid before k4 overwrites d_out with the real output.
  float* part  = (float*)d_out;
  float* part2 = (float*)((char*)d_out + 16777216);

  (void)hipMemsetAsync(ws + 196608, 0, 128, stream);
  k1_gramred<<<2 * CHUNKS, 256, 0, stream>>>(x, part, part2, cnt);
  kmid<<<16, 256, 0, stream>>>(part2, Wk, Wq, Wp, Wv, resc, Mbuf, Phi, cntM);
  k4_out<<<1536, 256, 0, stream>>>(x, Phi, bp, out);
}

// Round 4
// 184.863 us; speedup vs baseline: 1.9994x; 1.2273x over previous
//
#include <hip/hip_runtime.h>
#include <hip/hip_bf16.h>

typedef __bf16 bf16_t;
typedef __bf16 bf16x4 __attribute__((ext_vector_type(4)));
typedef __bf16 bf16x8 __attribute__((ext_vector_type(8)));
typedef float f32x4 __attribute__((ext_vector_type(4)));

#define NTOK 49152   // s*h*w = 3*128*128 tokens per batch
#define CDIM 128
#define CHUNKS 128   // split-K chunks for the Gram (grid = 256, 1 block/CU)
#define KT 384       // tokens per chunk
#define STEPS 12     // KT/32

__device__ inline f32x4 mfma16(bf16x8 a, bf16x8 b, f32x4 c) {
  return __builtin_amdgcn_mfma_f32_16x16x32_bf16(a, b, c, 0, 0, 0);
}

// Raw barrier: lgkmcnt(0) only (ds_writes visible), NO vmcnt drain -> the
// prefetch global loads stay in flight across the barrier.
#define BARRIER() do { asm volatile("s_waitcnt lgkmcnt(0)" ::: "memory"); \
    __builtin_amdgcn_s_barrier(); } while (0)

#define STAGE_LOAD(st, step)                               \
  {                                                        \
    const float* p_ = gsrc + (step) * 32;                  \
    st[0] = *(const f32x4*)(p_ + 0);                       \
    st[1] = *(const f32x4*)(p_ + 4);                       \
    st[2] = *(const f32x4*)(p_ + 8);                       \
    st[3] = *(const f32x4*)(p_ + 12);                      \
  }
#define CVT4(v) (bf16x4){(bf16_t)(v)[0], (bf16_t)(v)[1], (bf16_t)(v)[2], (bf16_t)(v)[3]}
#define STAGE_WRITE(st, buf)                               \
  {                                                        \
    bf16_t* t_ = &tile[buf][0];                            \
    *(bf16x4*)&t_[cg0 * 8 + 0] = CVT4(st[0]);              \
    *(bf16x4*)&t_[cg0 * 8 + 4] = CVT4(st[1]);              \
    *(bf16x4*)&t_[cg1 * 8 + 0] = CVT4(st[2]);              \
    *(bf16x4*)&t_[cg1 * 8 + 4] = CVT4(st[3]);              \
  }
#define MFMA_PHASE(buf)                                                     \
  {                                                                         \
    bf16x8 frag[8];                                                         \
    _Pragma("unroll")                                                       \
    for (int g = 0; g < 8; ++g)                                             \
      frag[g] = *(const bf16x8*)&tile[buf][(g * 64 + lane) * 8];            \
    bf16x8 a0, a1;                                                          \
    if (wave == 0)      { a0 = frag[0]; a1 = frag[1]; }                     \
    else if (wave == 1) { a0 = frag[2]; a1 = frag[3]; }                     \
    else if (wave == 2) { a0 = frag[4]; a1 = frag[5]; }                     \
    else                { a0 = frag[6]; a1 = frag[7]; }                     \
    _Pragma("unroll")                                                       \
    for (int j = 0; j < 8; ++j) {                                           \
      acc[0][j] = mfma16(a0, frag[j], acc[0][j]);                           \
      acc[1][j] = mfma16(a1, frag[j], acc[1][j]);                           \
    }                                                                       \
  }

// ---------------------------------------------------------------------------
// D1: Gram split-K, pure (round-1 proven body; the round-3 embedded tail
// reduction is REVERTED -- its device-scope fences in 256 blocks cost ~55 us
// of L2 writeback/invalidate across 8 XCDs). Frag-order f32x4 partial dump.
// ---------------------------------------------------------------------------
__global__ __launch_bounds__(256) void k1_gram(const float* __restrict__ x,
                                               float* __restrict__ part) {
  const int blk = blockIdx.x;
  const int b = blk >> 7, chunk = blk & 127;
  const float* Xb = x + (size_t)b * CDIM * NTOK;
  const int tid = threadIdx.x, wave = tid >> 6, lane = tid & 63;

  __shared__ __align__(16) bf16_t tile[2][128 * 32];

  const int sch = tid >> 1, shalf = tid & 1;
  const float* gsrc = Xb + (size_t)sch * NTOK + chunk * KT + shalf * 16;
  const int c16base = ((sch >> 4) << 6) + (sch & 15);
  const int cg0 = c16base + ((shalf * 2) << 4);
  const int cg1 = c16base + ((shalf * 2 + 1) << 4);

  f32x4 stA[4], stB[4];
  f32x4 acc[2][8];
#pragma unroll
  for (int t = 0; t < 2; ++t)
#pragma unroll
    for (int j = 0; j < 8; ++j) acc[t][j] = (f32x4){0.f, 0.f, 0.f, 0.f};

  STAGE_LOAD(stA, 0);
  STAGE_WRITE(stA, 0);
  STAGE_LOAD(stB, 1);
  BARRIER();

  for (int kk = 0; kk < STEPS; kk += 2) {
    if (kk + 2 < STEPS) STAGE_LOAD(stA, kk + 2);
    STAGE_WRITE(stB, 1);
    MFMA_PHASE(0);
    BARRIER();
    if (kk + 3 < STEPS) STAGE_LOAD(stB, kk + 3);
    if (kk + 2 < STEPS) STAGE_WRITE(stA, 0);
    MFMA_PHASE(1);
    BARRIER();
  }

  // Fragment-order dump: f32x4 index = (t*8+j)*256 + tid (decoded in kmid).
  float* pb = part + ((size_t)(b * CHUNKS + chunk) << 14);
#pragma unroll
  for (int t = 0; t < 2; ++t)
#pragma unroll
    for (int j = 0; j < 8; ++j)
      *(f32x4*)&pb[((((t * 8 + j) << 8) + tid) << 2)] = acc[t][j];
}

// ---------------------------------------------------------------------------
// D2: reduce 128 chunks -> 8 slice-partials of 16 chunks each (round-1
// proven). Also zeroes kmid's spin counters (this dispatch completes before
// kmid launches, so ordering is guaranteed by the stream).
// ---------------------------------------------------------------------------
__global__ __launch_bounds__(256) void k2a_reduce(const float* __restrict__ part,
                                                  float* __restrict__ part2,
                                                  int* __restrict__ cntM) {
  const int gid = blockIdx.x * 256 + threadIdx.x;  // 65536 threads
  if (gid < 2) cntM[gid] = 0;
  const int e4 = gid & 4095, sl = (gid >> 12) & 7, b = gid >> 15;
  const float* p = part + ((size_t)(b * CHUNKS + sl * 16) << 14) + e4 * 4;
  f32x4 s = (f32x4){0.f, 0.f, 0.f, 0.f};
#pragma unroll 8
  for (int i = 0; i < 16; ++i) s += *(const f32x4*)(p + ((size_t)i << 14));
  *(f32x4*)(part2 + ((size_t)(b * 8 + sl) << 14) + e4 * 4) = s;
}

// ---------------------------------------------------------------------------
// D3: kmid -- the entire middle in one dispatch (round-3 proven). grid 16.
// 16 blocks <= 256 CUs: all resident, so the bounded per-batch spin before
// the Phi phase is safe, and fences over 16 blocks are cheap.
// ---------------------------------------------------------------------------
__global__ __launch_bounds__(256) void kmid(const float* __restrict__ part2,
                                            const float* __restrict__ Wk,
                                            const float* __restrict__ Wq,
                                            const float* __restrict__ Wp,
                                            const float* __restrict__ Wv,
                                            const float* __restrict__ resc,
                                            float* __restrict__ Mbuf,
                                            bf16_t* __restrict__ Phi,
                                            int* __restrict__ cntM) {
  const int blk = blockIdx.x;  // 16 = b*8 + h
  const int b = blk >> 3, h = blk & 7;
  const int tid = threadIdx.x;

  __shared__ float S_l[128][132];            // padded: conflict-tamed
  __shared__ float Wk_l[16][128], Wq_l[16][128];
  __shared__ float Tk_l[16][132], Tq_l[16][132];
  __shared__ float A_l[16][16];
  __shared__ float dK[16], dQ[16];

  // ---- Phase A: S-sum + un-permute; stage W head rows ----
  {
    const float* p0 = part2 + ((size_t)(b * 8) << 14);
#pragma unroll 1
    for (int k = 0; k < 16; ++k) {
      const int g4 = k * 256 + tid;
      f32x4 s = (f32x4){0.f, 0.f, 0.f, 0.f};
#pragma unroll
      for (int sl = 0; sl < 8; ++sl)
        s += *(const f32x4*)(p0 + ((size_t)sl << 14) + g4 * 4);
      const int tj = g4 >> 8, t_ = tj >> 3, j_ = tj & 7;
      const int t2 = g4 & 255, w2 = t2 >> 6, q2 = (t2 >> 4) & 3, r2 = t2 & 15;
      const int row0 = w2 * 32 + t_ * 16 + q2 * 4, col = j_ * 16 + r2;
#pragma unroll
      for (int reg = 0; reg < 4; ++reg) S_l[row0 + reg][col] = s[reg];
    }
#pragma unroll
    for (int k = 0; k < 8; ++k) {
      const int idx = k * 256 + tid;  // 0..2047
      Wk_l[idx >> 7][idx & 127] = Wk[h * 2048 + idx];
      Wq_l[idx >> 7][idx & 127] = Wq[h * 2048 + idx];
    }
  }
  __syncthreads();

  // ---- Phase B: Tk/Tq. Thread owns d in {d2, d2+8}, j in [j0, j0+4). ----
  {
    const int d2 = tid >> 5;
    const int j0 = (tid & 31) * 4;
    f32x4 aK0 = (f32x4){0.f,0.f,0.f,0.f}, aK1 = (f32x4){0.f,0.f,0.f,0.f};
    f32x4 aQ0 = (f32x4){0.f,0.f,0.f,0.f}, aQ1 = (f32x4){0.f,0.f,0.f,0.f};
#pragma unroll 1
    for (int cb = 0; cb < 4; ++cb) {
      f32x4 wk0[8], wk1[8], wq0[8], wq1[8];
#pragma unroll
      for (int q = 0; q < 8; ++q) {
        wk0[q] = *(const f32x4*)&Wk_l[d2][cb * 32 + q * 4];
        wk1[q] = *(const f32x4*)&Wk_l[d2 + 8][cb * 32 + q * 4];
        wq0[q] = *(const f32x4*)&Wq_l[d2][cb * 32 + q * 4];
        wq1[q] = *(const f32x4*)&Wq_l[d2 + 8][cb * 32 + q * 4];
      }
#pragma unroll
      for (int q = 0; q < 8; ++q) {
#pragma unroll
        for (int cc = 0; cc < 4; ++cc) {
          const int c = cb * 32 + q * 4 + cc;
          const f32x4 sv = *(const f32x4*)&S_l[c][j0];  // S[c][j] == S[j][c]
          aK0 += sv * wk0[q][cc];
          aK1 += sv * wk1[q][cc];
          aQ0 += sv * wq0[q][cc];
          aQ1 += sv * wq1[q][cc];
        }
      }
    }
    *(f32x4*)&Tk_l[d2][j0]     = aK0;
    *(f32x4*)&Tk_l[d2 + 8][j0] = aK1;
    *(f32x4*)&Tq_l[d2][j0]     = aQ0;
    *(f32x4*)&Tq_l[d2 + 8][j0] = aQ1;
  }
  __syncthreads();

  // ---- Phase C: G, diagonals, softmax -> A_l ----
  {
    const int d = tid >> 4, e = tid & 15;
    f32x4 gacc = (f32x4){0.f,0.f,0.f,0.f};
    f32x4 kacc = (f32x4){0.f,0.f,0.f,0.f};
    f32x4 qacc = (f32x4){0.f,0.f,0.f,0.f};
#pragma unroll
    for (int j4 = 0; j4 < 32; ++j4) {
      const f32x4 tk = *(const f32x4*)&Tk_l[d][j4 * 4];
      const f32x4 wq = *(const f32x4*)&Wq_l[e][j4 * 4];
      gacc += tk * wq;
      if (e == 0) kacc += tk * (*(const f32x4*)&Wk_l[d][j4 * 4]);
      if (d == 0) qacc += (*(const f32x4*)&Tq_l[e][j4 * 4]) * wq;
    }
    if (e == 0) dK[d] = kacc[0] + kacc[1] + kacc[2] + kacc[3];
    if (d == 0) dQ[e] = qacc[0] + qacc[1] + qacc[2] + qacc[3];
    __syncthreads();
    const float g = gacc[0] + gacc[1] + gacc[2] + gacc[3];
    const float nk = fmaxf(sqrtf(fmaxf(dK[d], 0.f)), 1e-12f);
    const float nq = fmaxf(sqrtf(fmaxf(dQ[e], 0.f)), 1e-12f);
    float pre = g / (nk * nq) * resc[h];
    float mx = pre;
#pragma unroll
    for (int m = 1; m < 16; m <<= 1) mx = fmaxf(mx, __shfl_xor(mx, m, 64));
    const float p = expf(pre - mx);
    float sum = p;
#pragma unroll
    for (int m = 1; m < 16; m <<= 1) sum += __shfl_xor(sum, m, 64);
    A_l[d][e] = p / sum;
  }
  __syncthreads();

  // ---- Phase M: Mbuf[b][r][h*16+e] = sum_d Wp[r][h16+d] * A[d][e] ----
  {
    const int e = tid & 15, rg = tid >> 4;  // 16 r-groups x 8 rows
#pragma unroll
    for (int k = 0; k < 8; ++k) {
      const int r = rg * 8 + k;
      const f32x4* wp4 = (const f32x4*)(Wp + r * 128 + h * 16);
      float m = 0.f;
#pragma unroll
      for (int q = 0; q < 4; ++q) {
        const f32x4 w = wp4[q];
        m += w[0] * A_l[q * 4 + 0][e] + w[1] * A_l[q * 4 + 1][e] +
             w[2] * A_l[q * 4 + 2][e] + w[3] * A_l[q * 4 + 3][e];
      }
      Mbuf[(size_t)b * 16384 + r * 128 + h * 16 + e] = m;
    }
  }

  // publish M; wait for all 8 heads of this batch (all blocks resident).
  __threadfence();
  __syncthreads();
  if (tid == 0) {
    atomicAdd(&cntM[b], 1);
    while (__hip_atomic_load(&cntM[b], __ATOMIC_RELAXED,
                             __HIP_MEMORY_SCOPE_AGENT) < 8)
      __builtin_amdgcn_s_sleep(16);
  }
  __syncthreads();
  __threadfence();  // acquire: M rows from other heads' blocks

  // ---- Phi slice: columns h*16 .. h*16+15 of Phi[b] ----
  {
    const int cc = tid & 15, rg = tid >> 4;
    const float* Mb = Mbuf + (size_t)b * 16384;
    float pacc[8] = {0.f, 0.f, 0.f, 0.f, 0.f, 0.f, 0.f, 0.f};
#pragma unroll 2
    for (int j4 = 0; j4 < 32; ++j4) {
      float wv[4];
#pragma unroll
      for (int jj = 0; jj < 4; ++jj)
        wv[jj] = Wv[(j4 * 4 + jj) * 128 + h * 16 + cc];
#pragma unroll
      for (int k = 0; k < 8; ++k) {
        const f32x4 m4 = *(const f32x4*)&Mb[(rg * 8 + k) * 128 + j4 * 4];
        pacc[k] += m4[0] * wv[0] + m4[1] * wv[1] + m4[2] * wv[2] + m4[3] * wv[3];
      }
    }
#pragma unroll
    for (int k = 0; k < 8; ++k)
      Phi[((size_t)b << 14) + (rg * 8 + k) * 128 + h * 16 + cc] = (bf16_t)pacc[k];
  }
}

// ---------------------------------------------------------------------------
// D4: out[b] = Phi_b X_b + bp (unchanged proven kernel). grid 1536.
// ---------------------------------------------------------------------------
__global__ __launch_bounds__(256) void k4_out(const float* __restrict__ x,
                                              const bf16_t* __restrict__ Phi,
                                              const float* __restrict__ bp,
                                              float* __restrict__ out) {
  const int blk = blockIdx.x;
  const int b = blk / 768, tg = blk % 768;
  const float* Xb = x + (size_t)b * CDIM * NTOK;
  const bf16_t* Ph = Phi + ((size_t)b << 14);
  float* Ob = out + (size_t)b * CDIM * NTOK;
  const int tid = threadIdx.x, wave = tid >> 6, lane = tid & 63;
  const int r = lane & 15, quad = lane >> 4;
  const int tok0 = tg * 64;

  __shared__ __align__(16) char smem[64 * 68 * 4];
  bf16_t* tile = (bf16_t*)smem;
  float* tbuf = (float*)smem;

  {
    const int sch = tid >> 1, shalf = tid & 1;
    const float* p = Xb + (size_t)sch * NTOK + tok0 + shalf * 32;
    f32x4 st[8];
#pragma unroll
    for (int q = 0; q < 8; ++q) st[q] = *(const f32x4*)(p + q * 4);
    const int chunk_hi = ((sch >> 5) << 8) + (((sch >> 3) & 3) << 4);
    const int ei = sch & 7;
#pragma unroll
    for (int j = 0; j < 32; ++j) {
      const int tok = shalf * 32 + j;
      const int chunk = chunk_hi + ((tok >> 4) << 6) + (tok & 15);
      tile[chunk * 8 + ei] = (bf16_t)st[j >> 2][j & 3];
    }
  }
  __syncthreads();

  f32x4 acc[8];
#pragma unroll
  for (int m = 0; m < 8; ++m) acc[m] = (f32x4){0.f, 0.f, 0.f, 0.f};

#pragma unroll
  for (int step = 0; step < 4; ++step) {
    const bf16x8 bfr = *(const bf16x8*)&tile[(step * 256 + wave * 64 + lane) * 8];
#pragma unroll
    for (int m = 0; m < 8; ++m) {
      const bf16x8 ah = *(const bf16x8*)(Ph + (16 * m + r) * 128 + step * 32 + quad * 8);
      acc[m] = mfma16(ah, bfr, acc[m]);
    }
  }

  __syncthreads();
#pragma unroll
  for (int half = 0; half < 2; ++half) {
#pragma unroll
    for (int mm = 0; mm < 4; ++mm) {
#pragma unroll
      for (int reg = 0; reg < 4; ++reg)
        tbuf[(mm * 16 + quad * 4 + reg) * 68 + wave * 16 + r] = acc[half * 4 + mm][reg];
    }
    __syncthreads();
#pragma unroll
    for (int rep = 0; rep < 4; ++rep) {
      const int idx = rep * 256 + tid, rloc = idx >> 4, g = idx & 15;
      f32x4 v = *(const f32x4*)&tbuf[rloc * 68 + g * 4];
      const int row = half * 64 + rloc;
      const float bb = bp[row];
      v[0] += bb; v[1] += bb; v[2] += bb; v[3] += bb;
      *(f32x4*)&Ob[(size_t)row * NTOK + tok0 + g * 4] = v;
    }
    if (half == 0) __syncthreads();
  }
}

extern "C" void kernel_launch(void* const* d_in, const int* in_sizes, int n_in,
                              void* d_out, int out_size, void* d_ws, size_t ws_size,
                              hipStream_t stream) {
  const float* x    = (const float*)d_in[0];
  const float* Wq   = (const float*)d_in[1];
  const float* Wk   = (const float*)d_in[2];
  const float* Wv   = (const float*)d_in[3];
  const float* Wp   = (const float*)d_in[4];
  const float* bp   = (const float*)d_in[5];
  const float* resc = (const float*)d_in[6];
  float* out = (float*)d_out;

  // ws layout: Mbuf f32[2*128*128] @0 (131072 B) | Phi bf16[2*128*128]
  // @131072 (65536 B) | cntM[2] @196608 (zeroed by k2a before kmid runs).
  char* ws = (char*)d_ws;
  float*  Mbuf = (float*)(ws + 0);
  bf16_t* Phi  = (bf16_t*)(ws + 131072);
  int*    cntM = (int*)(ws + 196608);
  // Big scratch inside d_out (50.3 MB): part 16 MB + part2 1 MB, consumed by
  // kmid before k4 overwrites d_out with the real output.
  float* part  = (float*)d_out;
  float* part2 = (float*)((char*)d_out + 16777216);

  k1_gram<<<2 * CHUNKS, 256, 0, stream>>>(x, part);
  k2a_reduce<<<256, 256, 0, stream>>>(part, part2, cntM);
  kmid<<<16, 256, 0, stream>>>(part2, Wk, Wq, Wp, Wv, resc, Mbuf, Phi, cntM);
  k4_out<<<1536, 256, 0, stream>>>(x, Phi, bp, out);
}

// Round 5
// 178.610 us; speedup vs baseline: 2.0694x; 1.0350x over previous
//
#include <hip/hip_runtime.h>
#include <hip/hip_bf16.h>

typedef __bf16 bf16_t;
typedef __bf16 bf16x4 __attribute__((ext_vector_type(4)));
typedef __bf16 bf16x8 __attribute__((ext_vector_type(8)));
typedef float f32x4 __attribute__((ext_vector_type(4)));

#define NTOK 49152   // s*h*w = 3*128*128 tokens per batch
#define CDIM 128
#define CHUNKS 128   // split-K chunks for the Gram (grid = 256, 1 block/CU)
#define KT 384       // tokens per chunk
#define STEPS 12     // KT/32

__device__ inline f32x4 mfma16(bf16x8 a, bf16x8 b, f32x4 c) {
  return __builtin_amdgcn_mfma_f32_16x16x32_bf16(a, b, c, 0, 0, 0);
}

// Raw barrier: lgkmcnt(0) only (ds_writes visible), NO vmcnt drain -> the
// prefetch global loads stay in flight across the barrier.
#define BARRIER() do { asm volatile("s_waitcnt lgkmcnt(0)" ::: "memory"); \
    __builtin_amdgcn_s_barrier(); } while (0)

#define STAGE_LOAD(st, step)                               \
  {                                                        \
    const float* p_ = gsrc + (step) * 32;                  \
    st[0] = *(const f32x4*)(p_ + 0);                       \
    st[1] = *(const f32x4*)(p_ + 4);                       \
    st[2] = *(const f32x4*)(p_ + 8);                       \
    st[3] = *(const f32x4*)(p_ + 12);                      \
  }
#define CVT4(v) (bf16x4){(bf16_t)(v)[0], (bf16_t)(v)[1], (bf16_t)(v)[2], (bf16_t)(v)[3]}
#define STAGE_WRITE(st, buf)                               \
  {                                                        \
    bf16_t* t_ = &tile[buf][0];                            \
    *(bf16x4*)&t_[cg0 * 8 + 0] = CVT4(st[0]);              \
    *(bf16x4*)&t_[cg0 * 8 + 4] = CVT4(st[1]);              \
    *(bf16x4*)&t_[cg1 * 8 + 0] = CVT4(st[2]);              \
    *(bf16x4*)&t_[cg1 * 8 + 4] = CVT4(st[3]);              \
  }
#define MFMA_PHASE(buf)                                                     \
  {                                                                         \
    bf16x8 frag[8];                                                         \
    _Pragma("unroll")                                                       \
    for (int g = 0; g < 8; ++g)                                             \
      frag[g] = *(const bf16x8*)&tile[buf][(g * 64 + lane) * 8];            \
    bf16x8 a0, a1;                                                          \
    if (wave == 0)      { a0 = frag[0]; a1 = frag[1]; }                     \
    else if (wave == 1) { a0 = frag[2]; a1 = frag[3]; }                     \
    else if (wave == 2) { a0 = frag[4]; a1 = frag[5]; }                     \
    else                { a0 = frag[6]; a1 = frag[7]; }                     \
    _Pragma("unroll")                                                       \
    for (int j = 0; j < 8; ++j) {                                           \
      acc[0][j] = mfma16(a0, frag[j], acc[0][j]);                           \
      acc[1][j] = mfma16(a1, frag[j], acc[1][j]);                           \
    }                                                                       \
  }

// ---------------------------------------------------------------------------
// D1: Gram split-K (proven, unchanged). Frag-order f32x4 partial dump.
// ---------------------------------------------------------------------------
__global__ __launch_bounds__(256) void k1_gram(const float* __restrict__ x,
                                               float* __restrict__ part) {
  const int blk = blockIdx.x;
  const int b = blk >> 7, chunk = blk & 127;
  const float* Xb = x + (size_t)b * CDIM * NTOK;
  const int tid = threadIdx.x, wave = tid >> 6, lane = tid & 63;

  __shared__ __align__(16) bf16_t tile[2][128 * 32];

  const int sch = tid >> 1, shalf = tid & 1;
  const float* gsrc = Xb + (size_t)sch * NTOK + chunk * KT + shalf * 16;
  const int c16base = ((sch >> 4) << 6) + (sch & 15);
  const int cg0 = c16base + ((shalf * 2) << 4);
  const int cg1 = c16base + ((shalf * 2 + 1) << 4);

  f32x4 stA[4], stB[4];
  f32x4 acc[2][8];
#pragma unroll
  for (int t = 0; t < 2; ++t)
#pragma unroll
    for (int j = 0; j < 8; ++j) acc[t][j] = (f32x4){0.f, 0.f, 0.f, 0.f};

  STAGE_LOAD(stA, 0);
  STAGE_WRITE(stA, 0);
  STAGE_LOAD(stB, 1);
  BARRIER();

  for (int kk = 0; kk < STEPS; kk += 2) {
    if (kk + 2 < STEPS) STAGE_LOAD(stA, kk + 2);
    STAGE_WRITE(stB, 1);
    MFMA_PHASE(0);
    BARRIER();
    if (kk + 3 < STEPS) STAGE_LOAD(stB, kk + 3);
    if (kk + 2 < STEPS) STAGE_WRITE(stA, 0);
    MFMA_PHASE(1);
    BARRIER();
  }

  // Fragment-order dump: f32x4 index = (t*8+j)*256 + tid (decoded in k2s).
  float* pb = part + ((size_t)(b * CHUNKS + chunk) << 14);
#pragma unroll
  for (int t = 0; t < 2; ++t)
#pragma unroll
    for (int j = 0; j < 8; ++j)
      *(f32x4*)&pb[((((t * 8 + j) << 8) + tid) << 2)] = acc[t][j];
}

// ---------------------------------------------------------------------------
// D2: k2s -- direct 128-chunk sum -> S fp32, un-permuted row-major.
// 32768 threads, 1 per S element. Reads are coalesced per chunk-slice
// (64 lanes -> 256 B runs), 32 loads in flight to hide HBM latency.
// Replaces k2a + k2b (one fewer round-trip; no 8x duplicated reads later).
// ---------------------------------------------------------------------------
__global__ __launch_bounds__(256) void k2s(const float* __restrict__ part,
                                           float* __restrict__ S) {
  const int gid = blockIdx.x * 256 + threadIdx.x;  // 32768 = 2 * 16384
  const int e = gid & 16383, b = gid >> 14;
  const float* p = part + ((size_t)b << 21) + e;
  float a0 = 0.f, a1 = 0.f, a2 = 0.f, a3 = 0.f;
#pragma unroll 8
  for (int i = 0; i < 128; i += 4) {
    a0 += p[(size_t)(i + 0) << 14];
    a1 += p[(size_t)(i + 1) << 14];
    a2 += p[(size_t)(i + 2) << 14];
    a3 += p[(size_t)(i + 3) << 14];
  }
  const float s = (a0 + a1) + (a2 + a3);
  // frag-order decode (matches k1's dump exactly, scalar form of old k2b)
  const int g4 = e >> 2, rg = e & 3;
  const int tj = g4 >> 8, t = tj >> 3, j = tj & 7;
  const int t2 = g4 & 255, w2 = t2 >> 6, q2 = (t2 >> 4) & 3, r2 = t2 & 15;
  const int row = w2 * 32 + t * 16 + q2 * 4 + rg, col = j * 16 + r2;
  S[((size_t)b << 14) + row * 128 + col] = s;
}

// ---------------------------------------------------------------------------
// D3: kattn -- per (b,h): stage S (64 KB, L3-hot) + W head rows, compute
// Tk/Tq (verified kmid Phase B), G/diag/softmax (verified Phase C), write
// attn. No Mbuf round-trip, no fences, no spin.
// ---------------------------------------------------------------------------
__global__ __launch_bounds__(256) void kattn(const float* __restrict__ S,
                                             const float* __restrict__ Wk,
                                             const float* __restrict__ Wq,
                                             const float* __restrict__ resc,
                                             float* __restrict__ attn) {
  const int blk = blockIdx.x;  // 16 = b*8 + h
  const int b = blk >> 3, h = blk & 7;
  const int tid = threadIdx.x;

  __shared__ float S_l[128][132];
  __shared__ float Wk_l[16][128], Wq_l[16][128];
  __shared__ float Tk_l[16][132], Tq_l[16][132];
  __shared__ float dK[16], dQ[16];

  // ---- stage S_b (row-major) and W head rows ----
  {
    const float* Sb = S + ((size_t)b << 14);
#pragma unroll
    for (int q = 0; q < 16; ++q) {
      const int idx = q * 256 + tid;  // f32x4 id 0..4095
      const int row = idx >> 5, c4 = (idx & 31) << 2;
      *(f32x4*)&S_l[row][c4] = *(const f32x4*)(Sb + row * 128 + c4);
    }
#pragma unroll
    for (int k = 0; k < 8; ++k) {
      const int idx = k * 256 + tid;  // 0..2047
      Wk_l[idx >> 7][idx & 127] = Wk[h * 2048 + idx];
      Wq_l[idx >> 7][idx & 127] = Wq[h * 2048 + idx];
    }
  }
  __syncthreads();

  // ---- Phase B (verbatim): Tk/Tq. Thread owns d in {d2,d2+8}, j quad. ----
  {
    const int d2 = tid >> 5;
    const int j0 = (tid & 31) * 4;
    f32x4 aK0 = (f32x4){0.f,0.f,0.f,0.f}, aK1 = (f32x4){0.f,0.f,0.f,0.f};
    f32x4 aQ0 = (f32x4){0.f,0.f,0.f,0.f}, aQ1 = (f32x4){0.f,0.f,0.f,0.f};
#pragma unroll 1
    for (int cb = 0; cb < 4; ++cb) {
      f32x4 wk0[8], wk1[8], wq0[8], wq1[8];
#pragma unroll
      for (int q = 0; q < 8; ++q) {
        wk0[q] = *(const f32x4*)&Wk_l[d2][cb * 32 + q * 4];
        wk1[q] = *(const f32x4*)&Wk_l[d2 + 8][cb * 32 + q * 4];
        wq0[q] = *(const f32x4*)&Wq_l[d2][cb * 32 + q * 4];
        wq1[q] = *(const f32x4*)&Wq_l[d2 + 8][cb * 32 + q * 4];
      }
#pragma unroll
      for (int q = 0; q < 8; ++q) {
#pragma unroll
        for (int cc = 0; cc < 4; ++cc) {
          const int c = cb * 32 + q * 4 + cc;
          const f32x4 sv = *(const f32x4*)&S_l[c][j0];  // S[c][j] == S[j][c]
          aK0 += sv * wk0[q][cc];
          aK1 += sv * wk1[q][cc];
          aQ0 += sv * wq0[q][cc];
          aQ1 += sv * wq1[q][cc];
        }
      }
    }
    *(f32x4*)&Tk_l[d2][j0]     = aK0;
    *(f32x4*)&Tk_l[d2 + 8][j0] = aK1;
    *(f32x4*)&Tq_l[d2][j0]     = aQ0;
    *(f32x4*)&Tq_l[d2 + 8][j0] = aQ1;
  }
  __syncthreads();

  // ---- Phase C (verbatim): G, diagonals, softmax -> attn ----
  {
    const int d = tid >> 4, e = tid & 15;
    f32x4 gacc = (f32x4){0.f,0.f,0.f,0.f};
    f32x4 kacc = (f32x4){0.f,0.f,0.f,0.f};
    f32x4 qacc = (f32x4){0.f,0.f,0.f,0.f};
#pragma unroll
    for (int j4 = 0; j4 < 32; ++j4) {
      const f32x4 tk = *(const f32x4*)&Tk_l[d][j4 * 4];
      const f32x4 wq = *(const f32x4*)&Wq_l[e][j4 * 4];
      gacc += tk * wq;
      if (e == 0) kacc += tk * (*(const f32x4*)&Wk_l[d][j4 * 4]);
      if (d == 0) qacc += (*(const f32x4*)&Tq_l[e][j4 * 4]) * wq;
    }
    if (e == 0) dK[d] = kacc[0] + kacc[1] + kacc[2] + kacc[3];
    if (d == 0) dQ[e] = qacc[0] + qacc[1] + qacc[2] + qacc[3];
    __syncthreads();
    const float g = gacc[0] + gacc[1] + gacc[2] + gacc[3];
    const float nk = fmaxf(sqrtf(fmaxf(dK[d], 0.f)), 1e-12f);
    const float nq = fmaxf(sqrtf(fmaxf(dQ[e], 0.f)), 1e-12f);
    float pre = g / (nk * nq) * resc[h];
    float mx = pre;
#pragma unroll
    for (int m = 1; m < 16; m <<= 1) mx = fmaxf(mx, __shfl_xor(mx, m, 64));
    const float p = expf(pre - mx);
    float sum = p;
#pragma unroll
    for (int m = 1; m < 16; m <<= 1) sum += __shfl_xor(sum, m, 64);
    attn[blk * 256 + tid] = p / sum;
  }
}

// ---------------------------------------------------------------------------
// D4: k3_p (round-1 proven) -- Phi = Wp * blockdiag(attn) * Wv, bf16.
// ---------------------------------------------------------------------------
__global__ __launch_bounds__(256) void k3_p(const float* __restrict__ attn,
                                            const float* __restrict__ Wp,
                                            const float* __restrict__ Wv,
                                            bf16_t* __restrict__ Phi) {
  const int blk = blockIdx.x;  // 256 = b*128 + row
  const int b = blk >> 7, rrow = blk & 127;
  const int tid = threadIdx.x;
  __shared__ float M[128];
  if (tid < 128) {
    const int h = tid >> 4, e = tid & 15;
    const float* A = attn + (size_t)(b * 8 + h) * 256;
    const float* wp = Wp + rrow * 128 + h * 16;
    float m = 0.f;
#pragma unroll
    for (int d = 0; d < 16; ++d) m += wp[d] * A[d * 16 + e];
    M[tid] = m;
  }
  __syncthreads();
  if (tid < 128) {
    const int c = tid;
    float p = 0.f;
#pragma unroll 4
    for (int j = 0; j < 128; ++j) p += M[j] * Wv[j * 128 + c];
    Phi[((size_t)b << 14) + rrow * 128 + c] = (bf16_t)p;
  }
}

// ---------------------------------------------------------------------------
// D5: out[b] = Phi_b X_b + bp (proven, unchanged). grid 1536.
// ---------------------------------------------------------------------------
__global__ __launch_bounds__(256) void k4_out(const float* __restrict__ x,
                                              const bf16_t* __restrict__ Phi,
                                              const float* __restrict__ bp,
                                              float* __restrict__ out) {
  const int blk = blockIdx.x;
  const int b = blk / 768, tg = blk % 768;
  const float* Xb = x + (size_t)b * CDIM * NTOK;
  const bf16_t* Ph = Phi + ((size_t)b << 14);
  float* Ob = out + (size_t)b * CDIM * NTOK;
  const int tid = threadIdx.x, wave = tid >> 6, lane = tid & 63;
  const int r = lane & 15, quad = lane >> 4;
  const int tok0 = tg * 64;

  __shared__ __align__(16) char smem[64 * 68 * 4];
  bf16_t* tile = (bf16_t*)smem;
  float* tbuf = (float*)smem;

  {
    const int sch = tid >> 1, shalf = tid & 1;
    const float* p = Xb + (size_t)sch * NTOK + tok0 + shalf * 32;
    f32x4 st[8];
#pragma unroll
    for (int q = 0; q < 8; ++q) st[q] = *(const f32x4*)(p + q * 4);
    const int chunk_hi = ((sch >> 5) << 8) + (((sch >> 3) & 3) << 4);
    const int ei = sch & 7;
#pragma unroll
    for (int j = 0; j < 32; ++j) {
      const int tok = shalf * 32 + j;
      const int chunk = chunk_hi + ((tok >> 4) << 6) + (tok & 15);
      tile[chunk * 8 + ei] = (bf16_t)st[j >> 2][j & 3];
    }
  }
  __syncthreads();

  f32x4 acc[8];
#pragma unroll
  for (int m = 0; m < 8; ++m) acc[m] = (f32x4){0.f, 0.f, 0.f, 0.f};

#pragma unroll
  for (int step = 0; step < 4; ++step) {
    const bf16x8 bfr = *(const bf16x8*)&tile[(step * 256 + wave * 64 + lane) * 8];
#pragma unroll
    for (int m = 0; m < 8; ++m) {
      const bf16x8 ah = *(const bf16x8*)(Ph + (16 * m + r) * 128 + step * 32 + quad * 8);
      acc[m] = mfma16(ah, bfr, acc[m]);
    }
  }

  __syncthreads();
#pragma unroll
  for (int half = 0; half < 2; ++half) {
#pragma unroll
    for (int mm = 0; mm < 4; ++mm) {
#pragma unroll
      for (int reg = 0; reg < 4; ++reg)
        tbuf[(mm * 16 + quad * 4 + reg) * 68 + wave * 16 + r] = acc[half * 4 + mm][reg];
    }
    __syncthreads();
#pragma unroll
    for (int rep = 0; rep < 4; ++rep) {
      const int idx = rep * 256 + tid, rloc = idx >> 4, g = idx & 15;
      f32x4 v = *(const f32x4*)&tbuf[rloc * 68 + g * 4];
      const int row = half * 64 + rloc;
      const float bb = bp[row];
      v[0] += bb; v[1] += bb; v[2] += bb; v[3] += bb;
      *(f32x4*)&Ob[(size_t)row * NTOK + tok0 + g * 4] = v;
    }
    if (half == 0) __syncthreads();
  }
}

extern "C" void kernel_launch(void* const* d_in, const int* in_sizes, int n_in,
                              void* d_out, int out_size, void* d_ws, size_t ws_size,
                              hipStream_t stream) {
  const float* x    = (const float*)d_in[0];
  const float* Wq   = (const float*)d_in[1];
  const float* Wk   = (const float*)d_in[2];
  const float* Wv   = (const float*)d_in[3];
  const float* Wp   = (const float*)d_in[4];
  const float* bp   = (const float*)d_in[5];
  const float* resc = (const float*)d_in[6];
  float* out = (float*)d_out;

  // ws layout: S f32[2*128*128] @0 (131072 B) | attn f32[2*8*256] @131072
  // (16384 B) | Phi bf16[2*128*128] @147456 (65536 B). No counters needed.
  char* ws = (char*)d_ws;
  float*  S    = (float*)(ws + 0);
  float*  attn = (float*)(ws + 131072);
  bf16_t* Phi  = (bf16_t*)(ws + 147456);
  // Big scratch inside d_out (50.3 MB): part 16 MB, consumed by k2s before
  // k4 overwrites d_out with the real output.
  float* part  = (float*)d_out;

  k1_gram<<<2 * CHUNKS, 256, 0, stream>>>(x, part);
  k2s<<<128, 256, 0, stream>>>(part, S);
  kattn<<<16, 256, 0, stream>>>(S, Wk, Wq, resc, attn);
  k3_p<<<256, 256, 0, stream>>>(attn, Wp, Wv, Phi);
  k4_out<<<1536, 256, 0, stream>>>(x, Phi, bp, out);
}

// Round 6
// 174.333 us; speedup vs baseline: 2.1202x; 1.0245x over previous
//
#include <hip/hip_runtime.h>
#include <hip/hip_bf16.h>

typedef __bf16 bf16_t;
typedef __bf16 bf16x4 __attribute__((ext_vector_type(4)));
typedef __bf16 bf16x8 __attribute__((ext_vector_type(8)));
typedef float f32x4 __attribute__((ext_vector_type(4)));

#define NTOK 49152   // s*h*w = 3*128*128 tokens per batch
#define CDIM 128
#define CHUNKS 128   // split-K chunks for the Gram (grid = 256, 1 block/CU)
#define KT 384       // tokens per chunk
#define STEPS 12     // KT/32

__device__ inline f32x4 mfma16(bf16x8 a, bf16x8 b, f32x4 c) {
  return __builtin_amdgcn_mfma_f32_16x16x32_bf16(a, b, c, 0, 0, 0);
}

// Raw barrier: lgkmcnt(0) only (ds_writes visible), NO vmcnt drain -> the
// prefetch global loads stay in flight across the barrier.
#define BARRIER() do { asm volatile("s_waitcnt lgkmcnt(0)" ::: "memory"); \
    __builtin_amdgcn_s_barrier(); } while (0)

#define STAGE_LOAD(st, step)                               \
  {                                                        \
    const float* p_ = gsrc + (step) * 32;                  \
    st[0] = *(const f32x4*)(p_ + 0);                       \
    st[1] = *(const f32x4*)(p_ + 4);                       \
    st[2] = *(const f32x4*)(p_ + 8);                       \
    st[3] = *(const f32x4*)(p_ + 12);                      \
  }
#define CVT4(v) (bf16x4){(bf16_t)(v)[0], (bf16_t)(v)[1], (bf16_t)(v)[2], (bf16_t)(v)[3]}
#define STAGE_WRITE(st, buf)                               \
  {                                                        \
    bf16_t* t_ = &tile[buf][0];                            \
    *(bf16x4*)&t_[cg0 * 8 + 0] = CVT4(st[0]);              \
    *(bf16x4*)&t_[cg0 * 8 + 4] = CVT4(st[1]);              \
    *(bf16x4*)&t_[cg1 * 8 + 0] = CVT4(st[2]);              \
    *(bf16x4*)&t_[cg1 * 8 + 4] = CVT4(st[3]);              \
  }
#define MFMA_PHASE(buf)                                                     \
  {                                                                         \
    bf16x8 frag[8];                                                         \
    _Pragma("unroll")                                                       \
    for (int g = 0; g < 8; ++g)                                             \
      frag[g] = *(const bf16x8*)&tile[buf][(g * 64 + lane) * 8];            \
    bf16x8 a0, a1;                                                          \
    if (wave == 0)      { a0 = frag[0]; a1 = frag[1]; }                     \
    else if (wave == 1) { a0 = frag[2]; a1 = frag[3]; }                     \
    else if (wave == 2) { a0 = frag[4]; a1 = frag[5]; }                     \
    else                { a0 = frag[6]; a1 = frag[7]; }                     \
    _Pragma("unroll")                                                       \
    for (int j = 0; j < 8; ++j) {                                           \
      acc[0][j] = mfma16(a0, frag[j], acc[0][j]);                           \
      acc[1][j] = mfma16(a1, frag[j], acc[1][j]);                           \
    }                                                                       \
  }

// ---------------------------------------------------------------------------
// D1: Gram split-K (proven body). CHANGE vs R5: both next-step load batches
// issue in phase A (after WRITE(stB) frees stB), so 8 f32x4/thread (~32 KB/CU)
// are in flight across MFMA(0)+barrier instead of 4 -- enough to sustain HBM
// BW at 1 block/CU. Same loads, strictly earlier issue; semantics unchanged.
// ---------------------------------------------------------------------------
__global__ __launch_bounds__(256) void k1_gram(const float* __restrict__ x,
                                               float* __restrict__ part) {
  const int blk = blockIdx.x;
  const int b = blk >> 7, chunk = blk & 127;
  const float* Xb = x + (size_t)b * CDIM * NTOK;
  const int tid = threadIdx.x, wave = tid >> 6, lane = tid & 63;

  __shared__ __align__(16) bf16_t tile[2][128 * 32];

  const int sch = tid >> 1, shalf = tid & 1;
  const float* gsrc = Xb + (size_t)sch * NTOK + chunk * KT + shalf * 16;
  const int c16base = ((sch >> 4) << 6) + (sch & 15);
  const int cg0 = c16base + ((shalf * 2) << 4);
  const int cg1 = c16base + ((shalf * 2 + 1) << 4);

  f32x4 stA[4], stB[4];
  f32x4 acc[2][8];
#pragma unroll
  for (int t = 0; t < 2; ++t)
#pragma unroll
    for (int j = 0; j < 8; ++j) acc[t][j] = (f32x4){0.f, 0.f, 0.f, 0.f};

  STAGE_LOAD(stA, 0);
  STAGE_WRITE(stA, 0);
  STAGE_LOAD(stB, 1);
  BARRIER();

  for (int kk = 0; kk < STEPS; kk += 2) {
    // phase A: compute tile kk (buf0). Write kk+1 (stB), then issue BOTH
    // prefetches (kk+2 into stA, kk+3 into stB) before the MFMAs.
    if (kk + 2 < STEPS) STAGE_LOAD(stA, kk + 2);
    STAGE_WRITE(stB, 1);               // waits only stB (vmcnt counted)
    if (kk + 3 < STEPS) STAGE_LOAD(stB, kk + 3);
    MFMA_PHASE(0);
    BARRIER();
    // phase B: compute tile kk+1 (buf1); write kk+2 (stA->buf0).
    if (kk + 2 < STEPS) STAGE_WRITE(stA, 0);
    MFMA_PHASE(1);
    BARRIER();
  }

  // Fragment-order dump: f32x4 index = (t*8+j)*256 + tid (decoded in k2b).
  float* pb = part + ((size_t)(b * CHUNKS + chunk) << 14);
#pragma unroll
  for (int t = 0; t < 2; ++t)
#pragma unroll
    for (int j = 0; j < 8; ++j)
      *(f32x4*)&pb[((((t * 8 + j) << 8) + tid) << 2)] = acc[t][j];
}

// ---------------------------------------------------------------------------
// D2: k2a (R1-proven, verbatim): reduce 128 chunks -> 8 slice-partials of 16
// chunks each. 65536 threads, f32x4 loads, ~8 MB in flight -> full BW.
// ---------------------------------------------------------------------------
__global__ __launch_bounds__(256) void k2a_reduce(const float* __restrict__ part,
                                                  float* __restrict__ part2) {
  const int gid = blockIdx.x * 256 + threadIdx.x;  // 65536 threads
  const int e4 = gid & 4095, sl = (gid >> 12) & 7, b = gid >> 15;
  const float* p = part + ((size_t)(b * CHUNKS + sl * 16) << 14) + e4 * 4;
  f32x4 s = (f32x4){0.f, 0.f, 0.f, 0.f};
#pragma unroll 8
  for (int i = 0; i < 16; ++i) s += *(const f32x4*)(p + ((size_t)i << 14));
  *(f32x4*)(part2 + ((size_t)(b * 8 + sl) << 14) + e4 * 4) = s;
}

// ---------------------------------------------------------------------------
// D3: k2b (R1-proven, verbatim): sum 8 slices + un-permute -> S row-major.
// ---------------------------------------------------------------------------
__global__ __launch_bounds__(256) void k2b_reduce(const float* __restrict__ part2,
                                                  float* __restrict__ S) {
  const int gid = blockIdx.x * 256 + threadIdx.x;  // 8192 threads
  const int g4 = gid & 4095, b = gid >> 12;
  f32x4 s = (f32x4){0.f, 0.f, 0.f, 0.f};
#pragma unroll
  for (int sl = 0; sl < 8; ++sl)
    s += *(const f32x4*)(part2 + ((size_t)(b * 8 + sl) << 14) + g4 * 4);
  const int tj = g4 >> 8, t = tj >> 3, j = tj & 7;
  const int tid2 = g4 & 255, wave = tid2 >> 6, quad = (tid2 >> 4) & 3, r = tid2 & 15;
  const int row0 = wave * 32 + t * 16 + quad * 4, col = j * 16 + r;
  float* Sb = S + ((size_t)b << 14);
#pragma unroll
  for (int reg = 0; reg < 4; ++reg) Sb[(row0 + reg) * 128 + col] = s[reg];
}

// ---------------------------------------------------------------------------
// D4: kattn (R5-passing, verbatim): per (b,h) stage S + W head rows, Tk/Tq,
// G/diag/softmax -> attn. No fences, no spin.
// ---------------------------------------------------------------------------
__global__ __launch_bounds__(256) void kattn(const float* __restrict__ S,
                                             const float* __restrict__ Wk,
                                             const float* __restrict__ Wq,
                                             const float* __restrict__ resc,
                                             float* __restrict__ attn) {
  const int blk = blockIdx.x;  // 16 = b*8 + h
  const int b = blk >> 3, h = blk & 7;
  const int tid = threadIdx.x;

  __shared__ float S_l[128][132];
  __shared__ float Wk_l[16][128], Wq_l[16][128];
  __shared__ float Tk_l[16][132], Tq_l[16][132];
  __shared__ float dK[16], dQ[16];

  {
    const float* Sb = S + ((size_t)b << 14);
#pragma unroll
    for (int q = 0; q < 16; ++q) {
      const int idx = q * 256 + tid;  // f32x4 id 0..4095
      const int row = idx >> 5, c4 = (idx & 31) << 2;
      *(f32x4*)&S_l[row][c4] = *(const f32x4*)(Sb + row * 128 + c4);
    }
#pragma unroll
    for (int k = 0; k < 8; ++k) {
      const int idx = k * 256 + tid;  // 0..2047
      Wk_l[idx >> 7][idx & 127] = Wk[h * 2048 + idx];
      Wq_l[idx >> 7][idx & 127] = Wq[h * 2048 + idx];
    }
  }
  __syncthreads();

  {
    const int d2 = tid >> 5;
    const int j0 = (tid & 31) * 4;
    f32x4 aK0 = (f32x4){0.f,0.f,0.f,0.f}, aK1 = (f32x4){0.f,0.f,0.f,0.f};
    f32x4 aQ0 = (f32x4){0.f,0.f,0.f,0.f}, aQ1 = (f32x4){0.f,0.f,0.f,0.f};
#pragma unroll 1
    for (int cb = 0; cb < 4; ++cb) {
      f32x4 wk0[8], wk1[8], wq0[8], wq1[8];
#pragma unroll
      for (int q = 0; q < 8; ++q) {
        wk0[q] = *(const f32x4*)&Wk_l[d2][cb * 32 + q * 4];
        wk1[q] = *(const f32x4*)&Wk_l[d2 + 8][cb * 32 + q * 4];
        wq0[q] = *(const f32x4*)&Wq_l[d2][cb * 32 + q * 4];
        wq1[q] = *(const f32x4*)&Wq_l[d2 + 8][cb * 32 + q * 4];
      }
#pragma unroll
      for (int q = 0; q < 8; ++q) {
#pragma unroll
        for (int cc = 0; cc < 4; ++cc) {
          const int c = cb * 32 + q * 4 + cc;
          const f32x4 sv = *(const f32x4*)&S_l[c][j0];  // S[c][j] == S[j][c]
          aK0 += sv * wk0[q][cc];
          aK1 += sv * wk1[q][cc];
          aQ0 += sv * wq0[q][cc];
          aQ1 += sv * wq1[q][cc];
        }
      }
    }
    *(f32x4*)&Tk_l[d2][j0]     = aK0;
    *(f32x4*)&Tk_l[d2 + 8][j0] = aK1;
    *(f32x4*)&Tq_l[d2][j0]     = aQ0;
    *(f32x4*)&Tq_l[d2 + 8][j0] = aQ1;
  }
  __syncthreads();

  {
    const int d = tid >> 4, e = tid & 15;
    f32x4 gacc = (f32x4){0.f,0.f,0.f,0.f};
    f32x4 kacc = (f32x4){0.f,0.f,0.f,0.f};
    f32x4 qacc = (f32x4){0.f,0.f,0.f,0.f};
#pragma unroll
    for (int j4 = 0; j4 < 32; ++j4) {
      const f32x4 tk = *(const f32x4*)&Tk_l[d][j4 * 4];
      const f32x4 wq = *(const f32x4*)&Wq_l[e][j4 * 4];
      gacc += tk * wq;
      if (e == 0) kacc += tk * (*(const f32x4*)&Wk_l[d][j4 * 4]);
      if (d == 0) qacc += (*(const f32x4*)&Tq_l[e][j4 * 4]) * wq;
    }
    if (e == 0) dK[d] = kacc[0] + kacc[1] + kacc[2] + kacc[3];
    if (d == 0) dQ[e] = qacc[0] + qacc[1] + qacc[2] + qacc[3];
    __syncthreads();
    const float g = gacc[0] + gacc[1] + gacc[2] + gacc[3];
    const float nk = fmaxf(sqrtf(fmaxf(dK[d], 0.f)), 1e-12f);
    const float nq = fmaxf(sqrtf(fmaxf(dQ[e], 0.f)), 1e-12f);
    float pre = g / (nk * nq) * resc[h];
    float mx = pre;
#pragma unroll
    for (int m = 1; m < 16; m <<= 1) mx = fmaxf(mx, __shfl_xor(mx, m, 64));
    const float p = expf(pre - mx);
    float sum = p;
#pragma unroll
    for (int m = 1; m < 16; m <<= 1) sum += __shfl_xor(sum, m, 64);
    attn[blk * 256 + tid] = p / sum;
  }
}

// ---------------------------------------------------------------------------
// D5: k3_p (proven, verbatim) -- Phi = Wp * blockdiag(attn) * Wv, bf16.
// ---------------------------------------------------------------------------
__global__ __launch_bounds__(256) void k3_p(const float* __restrict__ attn,
                                            const float* __restrict__ Wp,
                                            const float* __restrict__ Wv,
                                            bf16_t* __restrict__ Phi) {
  const int blk = blockIdx.x;  // 256 = b*128 + row
  const int b = blk >> 7, rrow = blk & 127;
  const int tid = threadIdx.x;
  __shared__ float M[128];
  if (tid < 128) {
    const int h = tid >> 4, e = tid & 15;
    const float* A = attn + (size_t)(b * 8 + h) * 256;
    const float* wp = Wp + rrow * 128 + h * 16;
    float m = 0.f;
#pragma unroll
    for (int d = 0; d < 16; ++d) m += wp[d] * A[d * 16 + e];
    M[tid] = m;
  }
  __syncthreads();
  if (tid < 128) {
    const int c = tid;
    float p = 0.f;
#pragma unroll 4
    for (int j = 0; j < 128; ++j) p += M[j] * Wv[j * 128 + c];
    Phi[((size_t)b << 14) + rrow * 128 + c] = (bf16_t)p;
  }
}

// ---------------------------------------------------------------------------
// D6: out[b] = Phi_b X_b + bp (proven, verbatim). grid 1536.
// ---------------------------------------------------------------------------
__global__ __launch_bounds__(256) void k4_out(const float* __restrict__ x,
                                              const bf16_t* __restrict__ Phi,
                                              const float* __restrict__ bp,
                                              float* __restrict__ out) {
  const int blk = blockIdx.x;
  const int b = blk / 768, tg = blk % 768;
  const float* Xb = x + (size_t)b * CDIM * NTOK;
  const bf16_t* Ph = Phi + ((size_t)b << 14);
  float* Ob = out + (size_t)b * CDIM * NTOK;
  const int tid = threadIdx.x, wave = tid >> 6, lane = tid & 63;
  const int r = lane & 15, quad = lane >> 4;
  const int tok0 = tg * 64;

  __shared__ __align__(16) char smem[64 * 68 * 4];
  bf16_t* tile = (bf16_t*)smem;
  float* tbuf = (float*)smem;

  {
    const int sch = tid >> 1, shalf = tid & 1;
    const float* p = Xb + (size_t)sch * NTOK + tok0 + shalf * 32;
    f32x4 st[8];
#pragma unroll
    for (int q = 0; q < 8; ++q) st[q] = *(const f32x4*)(p + q * 4);
    const int chunk_hi = ((sch >> 5) << 8) + (((sch >> 3) & 3) << 4);
    const int ei = sch & 7;
#pragma unroll
    for (int j = 0; j < 32; ++j) {
      const int tok = shalf * 32 + j;
      const int chunk = chunk_hi + ((tok >> 4) << 6) + (tok & 15);
      tile[chunk * 8 + ei] = (bf16_t)st[j >> 2][j & 3];
    }
  }
  __syncthreads();

  f32x4 acc[8];
#pragma unroll
  for (int m = 0; m < 8; ++m) acc[m] = (f32x4){0.f, 0.f, 0.f, 0.f};

#pragma unroll
  for (int step = 0; step < 4; ++step) {
    const bf16x8 bfr = *(const bf16x8*)&tile[(step * 256 + wave * 64 + lane) * 8];
#pragma unroll
    for (int m = 0; m < 8; ++m) {
      const bf16x8 ah = *(const bf16x8*)(Ph + (16 * m + r) * 128 + step * 32 + quad * 8);
      acc[m] = mfma16(ah, bfr, acc[m]);
    }
  }

  __syncthreads();
#pragma unroll
  for (int half = 0; half < 2; ++half) {
#pragma unroll
    for (int mm = 0; mm < 4; ++mm) {
#pragma unroll
      for (int reg = 0; reg < 4; ++reg)
        tbuf[(mm * 16 + quad * 4 + reg) * 68 + wave * 16 + r] = acc[half * 4 + mm][reg];
    }
    __syncthreads();
#pragma unroll
    for (int rep = 0; rep < 4; ++rep) {
      const int idx = rep * 256 + tid, rloc = idx >> 4, g = idx & 15;
      f32x4 v = *(const f32x4*)&tbuf[rloc * 68 + g * 4];
      const int row = half * 64 + rloc;
      const float bb = bp[row];
      v[0] += bb; v[1] += bb; v[2] += bb; v[3] += bb;
      *(f32x4*)&Ob[(size_t)row * NTOK + tok0 + g * 4] = v;
    }
    if (half == 0) __syncthreads();
  }
}

extern "C" void kernel_launch(void* const* d_in, const int* in_sizes, int n_in,
                              void* d_out, int out_size, void* d_ws, size_t ws_size,
                              hipStream_t stream) {
  const float* x    = (const float*)d_in[0];
  const float* Wq   = (const float*)d_in[1];
  const float* Wk   = (const float*)d_in[2];
  const float* Wv   = (const float*)d_in[3];
  const float* Wp   = (const float*)d_in[4];
  const float* bp   = (const float*)d_in[5];
  const float* resc = (const float*)d_in[6];
  float* out = (float*)d_out;

  // ws layout: S f32[2*128*128] @0 (131072 B) | attn f32[2*8*256] @131072
  // (16384 B) | Phi bf16[2*128*128] @147456 (65536 B).
  char* ws = (char*)d_ws;
  float*  S    = (float*)(ws + 0);
  float*  attn = (float*)(ws + 131072);
  bf16_t* Phi  = (bf16_t*)(ws + 147456);
  // Big scratch inside d_out (50.3 MB): part 16 MB + part2 1 MB at +16 MB,
  // consumed (k2a/k2b) before k4 overwrites d_out with the real output.
  float* part  = (float*)d_out;
  float* part2 = (float*)((char*)d_out + 16777216);

  k1_gram<<<2 * CHUNKS, 256, 0, stream>>>(x, part);
  k2a_reduce<<<256, 256, 0, stream>>>(part, part2);
  k2b_reduce<<<32, 256, 0, stream>>>(part2, S);
  kattn<<<16, 256, 0, stream>>>(S, Wk, Wq, resc, attn);
  k3_p<<<256, 256, 0, stream>>>(attn, Wp, Wv, Phi);
  k4_out<<<1536, 256, 0, stream>>>(x, Phi, bp, out);
}

// Round 7
// 156.483 us; speedup vs baseline: 2.3621x; 1.1141x over previous
//
#include <hip/hip_runtime.h>
#include <hip/hip_bf16.h>

typedef __bf16 bf16_t;
typedef __bf16 bf16x4 __attribute__((ext_vector_type(4)));
typedef __bf16 bf16x8 __attribute__((ext_vector_type(8)));
typedef float f32x4 __attribute__((ext_vector_type(4)));

#define NTOK 49152   // s*h*w = 3*128*128 tokens per batch
#define CDIM 128
#define CHUNKS 128   // split-K chunks for the Gram (grid = 256, 1 block/CU)
#define KT 384       // tokens per chunk
#define STEPS 12     // KT/32

__device__ inline f32x4 mfma16(bf16x8 a, bf16x8 b, f32x4 c) {
  return __builtin_amdgcn_mfma_f32_16x16x32_bf16(a, b, c, 0, 0, 0);
}

// Raw barrier: lgkmcnt(0) only (ds_writes visible), NO vmcnt drain -> the
// prefetch global loads stay in flight across the barrier.
#define BARRIER() do { asm volatile("s_waitcnt lgkmcnt(0)" ::: "memory"); \
    __builtin_amdgcn_s_barrier(); } while (0)

#define STAGE_LOAD(st, step)                               \
  {                                                        \
    const float* p_ = gsrc + (step) * 32;                  \
    st[0] = *(const f32x4*)(p_ + 0);                       \
    st[1] = *(const f32x4*)(p_ + 4);                       \
    st[2] = *(const f32x4*)(p_ + 8);                       \
    st[3] = *(const f32x4*)(p_ + 12);                      \
  }
#define CVT4(v) (bf16x4){(bf16_t)(v)[0], (bf16_t)(v)[1], (bf16_t)(v)[2], (bf16_t)(v)[3]}
#define STAGE_WRITE(st, buf)                               \
  {                                                        \
    bf16_t* t_ = &tile[buf][0];                            \
    *(bf16x4*)&t_[cg0 * 8 + 0] = CVT4(st[0]);              \
    *(bf16x4*)&t_[cg0 * 8 + 4] = CVT4(st[1]);              \
    *(bf16x4*)&t_[cg1 * 8 + 0] = CVT4(st[2]);              \
    *(bf16x4*)&t_[cg1 * 8 + 4] = CVT4(st[3]);              \
  }
#define MFMA_PHASE(buf)                                                     \
  {                                                                         \
    bf16x8 frag[8];                                                         \
    _Pragma("unroll")                                                       \
    for (int g = 0; g < 8; ++g)                                             \
      frag[g] = *(const bf16x8*)&tile[buf][(g * 64 + lane) * 8];            \
    bf16x8 a0, a1;                                                          \
    if (wave == 0)      { a0 = frag[0]; a1 = frag[1]; }                     \
    else if (wave == 1) { a0 = frag[2]; a1 = frag[3]; }                     \
    else if (wave == 2) { a0 = frag[4]; a1 = frag[5]; }                     \
    else                { a0 = frag[6]; a1 = frag[7]; }                     \
    _Pragma("unroll")                                                       \
    for (int j = 0; j < 8; ++j) {                                           \
      acc[0][j] = mfma16(a0, frag[j], acc[0][j]);                           \
      acc[1][j] = mfma16(a1, frag[j], acc[1][j]);                           \
    }                                                                       \
  }

// ---------------------------------------------------------------------------
// D1: Gram split-K (R6-proven, verbatim). Frag-order f32x4 partial dump.
// ---------------------------------------------------------------------------
__global__ __launch_bounds__(256) void k1_gram(const float* __restrict__ x,
                                               float* __restrict__ part) {
  const int blk = blockIdx.x;
  const int b = blk >> 7, chunk = blk & 127;
  const float* Xb = x + (size_t)b * CDIM * NTOK;
  const int tid = threadIdx.x, wave = tid >> 6, lane = tid & 63;

  __shared__ __align__(16) bf16_t tile[2][128 * 32];

  const int sch = tid >> 1, shalf = tid & 1;
  const float* gsrc = Xb + (size_t)sch * NTOK + chunk * KT + shalf * 16;
  const int c16base = ((sch >> 4) << 6) + (sch & 15);
  const int cg0 = c16base + ((shalf * 2) << 4);
  const int cg1 = c16base + ((shalf * 2 + 1) << 4);

  f32x4 stA[4], stB[4];
  f32x4 acc[2][8];
#pragma unroll
  for (int t = 0; t < 2; ++t)
#pragma unroll
    for (int j = 0; j < 8; ++j) acc[t][j] = (f32x4){0.f, 0.f, 0.f, 0.f};

  STAGE_LOAD(stA, 0);
  STAGE_WRITE(stA, 0);
  STAGE_LOAD(stB, 1);
  BARRIER();

  for (int kk = 0; kk < STEPS; kk += 2) {
    if (kk + 2 < STEPS) STAGE_LOAD(stA, kk + 2);
    STAGE_WRITE(stB, 1);               // waits only stB (vmcnt counted)
    if (kk + 3 < STEPS) STAGE_LOAD(stB, kk + 3);
    MFMA_PHASE(0);
    BARRIER();
    if (kk + 2 < STEPS) STAGE_WRITE(stA, 0);
    MFMA_PHASE(1);
    BARRIER();
  }

  // Fragment-order dump: f32x4 index = (t*8+j)*256 + tid (decoded in k2b).
  float* pb = part + ((size_t)(b * CHUNKS + chunk) << 14);
#pragma unroll
  for (int t = 0; t < 2; ++t)
#pragma unroll
    for (int j = 0; j < 8; ++j)
      *(f32x4*)&pb[((((t * 8 + j) << 8) + tid) << 2)] = acc[t][j];
}

// ---------------------------------------------------------------------------
// D2: k2a (proven, verbatim): reduce 128 chunks -> 8 slice-partials.
// ---------------------------------------------------------------------------
__global__ __launch_bounds__(256) void k2a_reduce(const float* __restrict__ part,
                                                  float* __restrict__ part2) {
  const int gid = blockIdx.x * 256 + threadIdx.x;  // 65536 threads
  const int e4 = gid & 4095, sl = (gid >> 12) & 7, b = gid >> 15;
  const float* p = part + ((size_t)(b * CHUNKS + sl * 16) << 14) + e4 * 4;
  f32x4 s = (f32x4){0.f, 0.f, 0.f, 0.f};
#pragma unroll 8
  for (int i = 0; i < 16; ++i) s += *(const f32x4*)(p + ((size_t)i << 14));
  *(f32x4*)(part2 + ((size_t)(b * 8 + sl) << 14) + e4 * 4) = s;
}

// ---------------------------------------------------------------------------
// D3: k2b (proven, verbatim): sum 8 slices + un-permute -> S row-major.
// ---------------------------------------------------------------------------
__global__ __launch_bounds__(256) void k2b_reduce(const float* __restrict__ part2,
                                                  float* __restrict__ S) {
  const int gid = blockIdx.x * 256 + threadIdx.x;  // 8192 threads
  const int g4 = gid & 4095, b = gid >> 12;
  f32x4 s = (f32x4){0.f, 0.f, 0.f, 0.f};
#pragma unroll
  for (int sl = 0; sl < 8; ++sl)
    s += *(const f32x4*)(part2 + ((size_t)(b * 8 + sl) << 14) + g4 * 4);
  const int tj = g4 >> 8, t = tj >> 3, j = tj & 7;
  const int tid2 = g4 & 255, wave = tid2 >> 6, quad = (tid2 >> 4) & 3, r = tid2 & 15;
  const int row0 = wave * 32 + t * 16 + quad * 4, col = j * 16 + r;
  float* Sb = S + ((size_t)b << 14);
#pragma unroll
  for (int reg = 0; reg < 4; ++reg) Sb[(row0 + reg) * 128 + col] = s[reg];
}

// ---------------------------------------------------------------------------
// D4: kattn (proven, verbatim): per (b,h) stage S + W head rows, Tk/Tq,
// G/diag/softmax -> attn.
// ---------------------------------------------------------------------------
__global__ __launch_bounds__(256) void kattn(const float* __restrict__ S,
                                             const float* __restrict__ Wk,
                                             const float* __restrict__ Wq,
                                             const float* __restrict__ resc,
                                             float* __restrict__ attn) {
  const int blk = blockIdx.x;  // 16 = b*8 + h
  const int b = blk >> 3, h = blk & 7;
  const int tid = threadIdx.x;

  __shared__ float S_l[128][132];
  __shared__ float Wk_l[16][128], Wq_l[16][128];
  __shared__ float Tk_l[16][132], Tq_l[16][132];
  __shared__ float dK[16], dQ[16];

  {
    const float* Sb = S + ((size_t)b << 14);
#pragma unroll
    for (int q = 0; q < 16; ++q) {
      const int idx = q * 256 + tid;  // f32x4 id 0..4095
      const int row = idx >> 5, c4 = (idx & 31) << 2;
      *(f32x4*)&S_l[row][c4] = *(const f32x4*)(Sb + row * 128 + c4);
    }
#pragma unroll
    for (int k = 0; k < 8; ++k) {
      const int idx = k * 256 + tid;  // 0..2047
      Wk_l[idx >> 7][idx & 127] = Wk[h * 2048 + idx];
      Wq_l[idx >> 7][idx & 127] = Wq[h * 2048 + idx];
    }
  }
  __syncthreads();

  {
    const int d2 = tid >> 5;
    const int j0 = (tid & 31) * 4;
    f32x4 aK0 = (f32x4){0.f,0.f,0.f,0.f}, aK1 = (f32x4){0.f,0.f,0.f,0.f};
    f32x4 aQ0 = (f32x4){0.f,0.f,0.f,0.f}, aQ1 = (f32x4){0.f,0.f,0.f,0.f};
#pragma unroll 1
    for (int cb = 0; cb < 4; ++cb) {
      f32x4 wk0[8], wk1[8], wq0[8], wq1[8];
#pragma unroll
      for (int q = 0; q < 8; ++q) {
        wk0[q] = *(const f32x4*)&Wk_l[d2][cb * 32 + q * 4];
        wk1[q] = *(const f32x4*)&Wk_l[d2 + 8][cb * 32 + q * 4];
        wq0[q] = *(const f32x4*)&Wq_l[d2][cb * 32 + q * 4];
        wq1[q] = *(const f32x4*)&Wq_l[d2 + 8][cb * 32 + q * 4];
      }
#pragma unroll
      for (int q = 0; q < 8; ++q) {
#pragma unroll
        for (int cc = 0; cc < 4; ++cc) {
          const int c = cb * 32 + q * 4 + cc;
          const f32x4 sv = *(const f32x4*)&S_l[c][j0];  // S[c][j] == S[j][c]
          aK0 += sv * wk0[q][cc];
          aK1 += sv * wk1[q][cc];
          aQ0 += sv * wq0[q][cc];
          aQ1 += sv * wq1[q][cc];
        }
      }
    }
    *(f32x4*)&Tk_l[d2][j0]     = aK0;
    *(f32x4*)&Tk_l[d2 + 8][j0] = aK1;
    *(f32x4*)&Tq_l[d2][j0]     = aQ0;
    *(f32x4*)&Tq_l[d2 + 8][j0] = aQ1;
  }
  __syncthreads();

  {
    const int d = tid >> 4, e = tid & 15;
    f32x4 gacc = (f32x4){0.f,0.f,0.f,0.f};
    f32x4 kacc = (f32x4){0.f,0.f,0.f,0.f};
    f32x4 qacc = (f32x4){0.f,0.f,0.f,0.f};
#pragma unroll
    for (int j4 = 0; j4 < 32; ++j4) {
      const f32x4 tk = *(const f32x4*)&Tk_l[d][j4 * 4];
      const f32x4 wq = *(const f32x4*)&Wq_l[e][j4 * 4];
      gacc += tk * wq;
      if (e == 0) kacc += tk * (*(const f32x4*)&Wk_l[d][j4 * 4]);
      if (d == 0) qacc += (*(const f32x4*)&Tq_l[e][j4 * 4]) * wq;
    }
    if (e == 0) dK[d] = kacc[0] + kacc[1] + kacc[2] + kacc[3];
    if (d == 0) dQ[e] = qacc[0] + qacc[1] + qacc[2] + qacc[3];
    __syncthreads();
    const float g = gacc[0] + gacc[1] + gacc[2] + gacc[3];
    const float nk = fmaxf(sqrtf(fmaxf(dK[d], 0.f)), 1e-12f);
    const float nq = fmaxf(sqrtf(fmaxf(dQ[e], 0.f)), 1e-12f);
    float pre = g / (nk * nq) * resc[h];
    float mx = pre;
#pragma unroll
    for (int m = 1; m < 16; m <<= 1) mx = fmaxf(mx, __shfl_xor(mx, m, 64));
    const float p = expf(pre - mx);
    float sum = p;
#pragma unroll
    for (int m = 1; m < 16; m <<= 1) sum += __shfl_xor(sum, m, 64);
    attn[blk * 256 + tid] = p / sum;
  }
}

// ---------------------------------------------------------------------------
// D5: k3_p (proven, verbatim) -- Phi = Wp * blockdiag(attn) * Wv, bf16.
// ---------------------------------------------------------------------------
__global__ __launch_bounds__(256) void k3_p(const float* __restrict__ attn,
                                            const float* __restrict__ Wp,
                                            const float* __restrict__ Wv,
                                            bf16_t* __restrict__ Phi) {
  const int blk = blockIdx.x;  // 256 = b*128 + row
  const int b = blk >> 7, rrow = blk & 127;
  const int tid = threadIdx.x;
  __shared__ float M[128];
  if (tid < 128) {
    const int h = tid >> 4, e = tid & 15;
    const float* A = attn + (size_t)(b * 8 + h) * 256;
    const float* wp = Wp + rrow * 128 + h * 16;
    float m = 0.f;
#pragma unroll
    for (int d = 0; d < 16; ++d) m += wp[d] * A[d * 16 + e];
    M[tid] = m;
  }
  __syncthreads();
  if (tid < 128) {
    const int c = tid;
    float p = 0.f;
#pragma unroll 4
    for (int j = 0; j < 128; ++j) p += M[j] * Wv[j * 128 + c];
    Phi[((size_t)b << 14) + rrow * 128 + c] = (bf16_t)p;
  }
}

// ---------------------------------------------------------------------------
// D6: out[b] = Phi_b X_b + bp. CHANGES vs R6 (theory: k4 operand traffic):
// (1) XOR bank-swizzle on the X staging scatter + matching bfr read
//     (chunk ^= (chunk>>4)&3, an involution; read side (rc>>4)&3 == quad ==
//     write side (ch>>3)&3). Before: chunk%8 wave-constant -> ~16-way write
//     conflict (R2: ~1.3M conflict cycles). After: ~2-4-way.
// (2) Phi staged once per block into LDS (row pitch 136 bf16 = 272 B, 16B
//     aligned; ah-read banks 4(r+quad)+16step -> uniform, conflict-free).
//     Kills ~200 MB of duplicated L2 reads (32 KB read 3000x). tbuf aliases
//     Phi_l (dead after MFMA). LDS 51200 B -> 3 blocks/CU, 12 waves.
// ---------------------------------------------------------------------------
__global__ __launch_bounds__(256) void k4_out(const float* __restrict__ x,
                                              const bf16_t* __restrict__ Phi,
                                              const float* __restrict__ bp,
                                              float* __restrict__ out) {
  const int blk = blockIdx.x;
  const int b = blk / 768, tg = blk % 768;
  const float* Xb = x + (size_t)b * CDIM * NTOK;
  const bf16_t* Ph = Phi + ((size_t)b << 14);
  float* Ob = out + (size_t)b * CDIM * NTOK;
  const int tid = threadIdx.x, wave = tid >> 6, lane = tid & 63;
  const int r = lane & 15, quad = lane >> 4;
  const int tok0 = tg * 64;

  __shared__ __align__(16) char smem[16384 + 34816];  // tile | Phi_l (tbuf aliases Phi_l)
  bf16_t* tile = (bf16_t*)smem;
  bf16_t* Phl = (bf16_t*)(smem + 16384);
  float* tbuf = (float*)(smem + 16384);

  // ---- stage Phi -> LDS (pitch 136) ----
#pragma unroll
  for (int i = 0; i < 8; ++i) {
    const int g = i * 256 + tid;           // 2048 x 16B chunks
    const int prow = g >> 4, pc = g & 15;
    *(bf16x8*)&Phl[prow * 136 + pc * 8] = *(const bf16x8*)(Ph + prow * 128 + pc * 8);
  }

  // ---- stage X tile (fp32 -> bf16, frag order, XOR-swizzled) ----
  {
    const int sch = tid >> 1, shalf = tid & 1;
    const float* p = Xb + (size_t)sch * NTOK + tok0 + shalf * 32;
    f32x4 st[8];
#pragma unroll
    for (int q = 0; q < 8; ++q) st[q] = *(const f32x4*)(p + q * 4);
    const int chunk_hi = ((sch >> 5) << 8) + (((sch >> 3) & 3) << 4);
    const int ei = sch & 7;
#pragma unroll
    for (int j = 0; j < 32; ++j) {
      const int tok = shalf * 32 + j;
      const int chunk = chunk_hi + ((tok >> 4) << 6) + (tok & 15);
      const int sw = chunk ^ ((chunk >> 4) & 3);   // bank-spread involution
      tile[sw * 8 + ei] = (bf16_t)st[j >> 2][j & 3];
    }
  }
  __syncthreads();

  f32x4 acc[8];
#pragma unroll
  for (int m = 0; m < 8; ++m) acc[m] = (f32x4){0.f, 0.f, 0.f, 0.f};

#pragma unroll
  for (int step = 0; step < 4; ++step) {
    const int rc = step * 256 + wave * 64 + lane;
    const bf16x8 bfr = *(const bf16x8*)&tile[(rc ^ ((rc >> 4) & 3)) * 8];
#pragma unroll
    for (int m = 0; m < 8; ++m) {
      const bf16x8 ah = *(const bf16x8*)&Phl[(16 * m + r) * 136 + step * 32 + quad * 8];
      acc[m] = mfma16(ah, bfr, acc[m]);
    }
  }

  __syncthreads();  // MFMA done: tile + Phi_l dead, tbuf reuse safe
#pragma unroll
  for (int half = 0; half < 2; ++half) {
#pragma unroll
    for (int mm = 0; mm < 4; ++mm) {
#pragma unroll
      for (int reg = 0; reg < 4; ++reg)
        tbuf[(mm * 16 + quad * 4 + reg) * 68 + wave * 16 + r] = acc[half * 4 + mm][reg];
    }
    __syncthreads();
#pragma unroll
    for (int rep = 0; rep < 4; ++rep) {
      const int idx = rep * 256 + tid, rloc = idx >> 4, g = idx & 15;
      f32x4 v = *(const f32x4*)&tbuf[rloc * 68 + g * 4];
      const int row = half * 64 + rloc;
      const float bb = bp[row];
      v[0] += bb; v[1] += bb; v[2] += bb; v[3] += bb;
      *(f32x4*)&Ob[(size_t)row * NTOK + tok0 + g * 4] = v;
    }
    if (half == 0) __syncthreads();
  }
}

extern "C" void kernel_launch(void* const* d_in, const int* in_sizes, int n_in,
                              void* d_out, int out_size, void* d_ws, size_t ws_size,
                              hipStream_t stream) {
  const float* x    = (const float*)d_in[0];
  const float* Wq   = (const float*)d_in[1];
  const float* Wk   = (const float*)d_in[2];
  const float* Wv   = (const float*)d_in[3];
  const float* Wp   = (const float*)d_in[4];
  const float* bp   = (const float*)d_in[5];
  const float* resc = (const float*)d_in[6];
  float* out = (float*)d_out;

  // ws layout: S f32[2*128*128] @0 (131072 B) | attn f32[2*8*256] @131072
  // (16384 B) | Phi bf16[2*128*128] @147456 (65536 B).
  char* ws = (char*)d_ws;
  float*  S    = (float*)(ws + 0);
  float*  attn = (float*)(ws + 131072);
  bf16_t* Phi  = (bf16_t*)(ws + 147456);
  // Big scratch inside d_out (50.3 MB): part 16 MB + part2 1 MB at +16 MB,
  // consumed (k2a/k2b) before k4 overwrites d_out with the real output.
  float* part  = (float*)d_out;
  float* part2 = (float*)((char*)d_out + 16777216);

  k1_gram<<<2 * CHUNKS, 256, 0, stream>>>(x, part);
  k2a_reduce<<<256, 256, 0, stream>>>(part, part2);
  k2b_reduce<<<32, 256, 0, stream>>>(part2, S);
  kattn<<<16, 256, 0, stream>>>(S, Wk, Wq, resc, attn);
  k3_p<<<256, 256, 0, stream>>>(attn, Wp, Wv, Phi);
  k4_out<<<1536, 256, 0, stream>>>(x, Phi, bp, out);
}

// Round 9
// 155.553 us; speedup vs baseline: 2.3762x; 1.0060x over previous
//
#include <hip/hip_runtime.h>
#include <hip/hip_bf16.h>

typedef __bf16 bf16_t;
typedef __bf16 bf16x4 __attribute__((ext_vector_type(4)));
typedef __bf16 bf16x8 __attribute__((ext_vector_type(8)));
typedef float f32x4 __attribute__((ext_vector_type(4)));

#define NTOK 49152   // s*h*w = 3*128*128 tokens per batch
#define CDIM 128
#define CHUNKS 128   // split-K chunks for the Gram (grid = 256, 1 block/CU)
#define KT 384       // tokens per chunk
#define STEPS 12     // KT/32

__device__ inline f32x4 mfma16(bf16x8 a, bf16x8 b, f32x4 c) {
  return __builtin_amdgcn_mfma_f32_16x16x32_bf16(a, b, c, 0, 0, 0);
}

// Raw barrier: lgkmcnt(0) only (ds_writes visible), NO vmcnt drain -> the
// prefetch global loads stay in flight across the barrier.
#define BARRIER() do { asm volatile("s_waitcnt lgkmcnt(0)" ::: "memory"); \
    __builtin_amdgcn_s_barrier(); } while (0)

// ---------------------------------------------------------------------------
// D1: Gram split-K. 512 threads / 8 waves per block (grid 256 -> 1 block/CU,
// 2 waves/SIMD for intra-phase ILP: one wave's MFMA issue overlaps the
// other's ds_read latency). Each wave owns one 16-row block (a = frag[wave]);
// staging is ONE ds_write_b128 per thread per step; epilogue is 8 f32x4
// stores/thread. Same per-element accumulation order -> S bitwise identical;
// only the dump permutation changes (decoded in k2b).
// ---------------------------------------------------------------------------
__global__ __launch_bounds__(512) void k1_gram(const float* __restrict__ x,
                                               float* __restrict__ part) {
  const int blk = blockIdx.x;
  const int b = blk >> 7, chunk = blk & 127;
  const float* Xb = x + (size_t)b * CDIM * NTOK;
  const int tid = threadIdx.x, wave = tid >> 6, lane = tid & 63;

  __shared__ __align__(16) bf16_t tile[2][128 * 32];  // frag-ordered, 8 KB each

  // Staging map: thread t -> ch = t>>2, 8-tok group sq = t&3.
  const int sch = tid >> 2, sq = tid & 3;
  const float* gsrc = Xb + (size_t)sch * NTOK + chunk * KT + sq * 8;
  // This thread's single 16B fragment chunk within a 32-tok step:
  const int c16 = ((sch >> 4) << 6) + (sq << 4) + (sch & 15);

  f32x4 stA[2], stB[2];
#define STAGE_LOAD(st, step)                               \
  {                                                        \
    const float* p_ = gsrc + (step) * 32;                  \
    st[0] = *(const f32x4*)(p_ + 0);                       \
    st[1] = *(const f32x4*)(p_ + 4);                       \
  }
#define STAGE_WRITE(st, buf)                                              \
  {                                                                       \
    *(bf16x8*)&tile[buf][c16 * 8] = (bf16x8){                             \
        (bf16_t)st[0][0], (bf16_t)st[0][1], (bf16_t)st[0][2],             \
        (bf16_t)st[0][3], (bf16_t)st[1][0], (bf16_t)st[1][1],             \
        (bf16_t)st[1][2], (bf16_t)st[1][3]};                              \
  }

  f32x4 acc[8];
#pragma unroll
  for (int j = 0; j < 8; ++j) acc[j] = (f32x4){0.f, 0.f, 0.f, 0.f};

#define MFMA_PHASE(buf)                                                     \
  {                                                                         \
    bf16x8 frag[8];                                                         \
    _Pragma("unroll")                                                       \
    for (int g = 0; g < 8; ++g)                                             \
      frag[g] = *(const bf16x8*)&tile[buf][(g * 64 + lane) * 8];            \
    bf16x8 a;                                                               \
    if (wave == 0)      a = frag[0];                                        \
    else if (wave == 1) a = frag[1];                                        \
    else if (wave == 2) a = frag[2];                                        \
    else if (wave == 3) a = frag[3];                                        \
    else if (wave == 4) a = frag[4];                                        \
    else if (wave == 5) a = frag[5];                                        \
    else if (wave == 6) a = frag[6];                                        \
    else                a = frag[7];                                        \
    _Pragma("unroll")                                                       \
    for (int j = 0; j < 8; ++j) acc[j] = mfma16(a, frag[j], acc[j]);        \
  }

  // Prologue: tile0 -> LDS0, tile1 loads in flight across the barrier.
  STAGE_LOAD(stA, 0);
  STAGE_WRITE(stA, 0);
  STAGE_LOAD(stB, 1);
  BARRIER();

  for (int kk = 0; kk < STEPS; kk += 2) {
    if (kk + 2 < STEPS) STAGE_LOAD(stA, kk + 2);
    STAGE_WRITE(stB, 1);               // waits only stB (vmcnt counted)
    if (kk + 3 < STEPS) STAGE_LOAD(stB, kk + 3);
    MFMA_PHASE(0);
    BARRIER();
    if (kk + 2 < STEPS) STAGE_WRITE(stA, 0);
    MFMA_PHASE(1);
    BARRIER();
  }
#undef STAGE_LOAD
#undef STAGE_WRITE
#undef MFMA_PHASE

  // Fragment-order dump: f32x4 index = j*512 + tid (decoded in k2b).
  // (row = wave*16 + quad*4 + reg, col = j*16 + r)
  float* pb = part + ((size_t)(b * CHUNKS + chunk) << 14);
#pragma unroll
  for (int j = 0; j < 8; ++j)
    *(f32x4*)&pb[(((j << 9) + tid) << 2)] = acc[j];
}

// ---------------------------------------------------------------------------
// D2: k2a (proven, verbatim; layout-agnostic element-wise sum):
// reduce 128 chunks -> 8 slice-partials of 16 chunks each.
// ---------------------------------------------------------------------------
__global__ __launch_bounds__(256) void k2a_reduce(const float* __restrict__ part,
                                                  float* __restrict__ part2) {
  const int gid = blockIdx.x * 256 + threadIdx.x;  // 65536 threads
  const int e4 = gid & 4095, sl = (gid >> 12) & 7, b = gid >> 15;
  const float* p = part + ((size_t)(b * CHUNKS + sl * 16) << 14) + e4 * 4;
  f32x4 s = (f32x4){0.f, 0.f, 0.f, 0.f};
#pragma unroll 8
  for (int i = 0; i < 16; ++i) s += *(const f32x4*)(p + ((size_t)i << 14));
  *(f32x4*)(part2 + ((size_t)(b * 8 + sl) << 14) + e4 * 4) = s;
}

// ---------------------------------------------------------------------------
// D3: k2b: sum 8 slices + un-permute (8-wave decode) -> S row-major.
// ---------------------------------------------------------------------------
__global__ __launch_bounds__(256) void k2b_reduce(const float* __restrict__ part2,
                                                  float* __restrict__ S) {
  const int gid = blockIdx.x * 256 + threadIdx.x;  // 8192 threads
  const int g4 = gid & 4095, b = gid >> 12;
  f32x4 s = (f32x4){0.f, 0.f, 0.f, 0.f};
#pragma unroll
  for (int sl = 0; sl < 8; ++sl)
    s += *(const f32x4*)(part2 + ((size_t)(b * 8 + sl) << 14) + g4 * 4);
  // 8-wave frag-order decode: g4 = j*512 + tid; tid = wave*64 + quad*16 + r
  const int j = g4 >> 9, tid2 = g4 & 511;
  const int wave = tid2 >> 6, quad = (tid2 >> 4) & 3, r = tid2 & 15;
  const int row0 = wave * 16 + quad * 4, col = j * 16 + r;
  float* Sb = S + ((size_t)b << 14);
#pragma unroll
  for (int reg = 0; reg < 4; ++reg) Sb[(row0 + reg) * 128 + col] = s[reg];
}

// ---------------------------------------------------------------------------
// D4: kattn (proven, verbatim): per (b,h) stage S + W head rows, Tk/Tq,
// G/diag/softmax -> attn.
// ---------------------------------------------------------------------------
__global__ __launch_bounds__(256) void kattn(const float* __restrict__ S,
                                             const float* __restrict__ Wk,
                                             const float* __restrict__ Wq,
                                             const float* __restrict__ resc,
                                             float* __restrict__ attn) {
  const int blk = blockIdx.x;  // 16 = b*8 + h
  const int b = blk >> 3, h = blk & 7;
  const int tid = threadIdx.x;

  __shared__ float S_l[128][132];
  __shared__ float Wk_l[16][128], Wq_l[16][128];
  __shared__ float Tk_l[16][132], Tq_l[16][132];
  __shared__ float dK[16], dQ[16];

  {
    const float* Sb = S + ((size_t)b << 14);
#pragma unroll
    for (int q = 0; q < 16; ++q) {
      const int idx = q * 256 + tid;  // f32x4 id 0..4095
      const int row = idx >> 5, c4 = (idx & 31) << 2;
      *(f32x4*)&S_l[row][c4] = *(const f32x4*)(Sb + row * 128 + c4);
    }
#pragma unroll
    for (int k = 0; k < 8; ++k) {
      const int idx = k * 256 + tid;  // 0..2047
      Wk_l[idx >> 7][idx & 127] = Wk[h * 2048 + idx];
      Wq_l[idx >> 7][idx & 127] = Wq[h * 2048 + idx];
    }
  }
  __syncthreads();

  {
    const int d2 = tid >> 5;
    const int j0 = (tid & 31) * 4;
    f32x4 aK0 = (f32x4){0.f,0.f,0.f,0.f}, aK1 = (f32x4){0.f,0.f,0.f,0.f};
    f32x4 aQ0 = (f32x4){0.f,0.f,0.f,0.f}, aQ1 = (f32x4){0.f,0.f,0.f,0.f};
#pragma unroll 1
    for (int cb = 0; cb < 4; ++cb) {
      f32x4 wk0[8], wk1[8], wq0[8], wq1[8];
#pragma unroll
      for (int q = 0; q < 8; ++q) {
        wk0[q] = *(const f32x4*)&Wk_l[d2][cb * 32 + q * 4];
        wk1[q] = *(const f32x4*)&Wk_l[d2 + 8][cb * 32 + q * 4];
        wq0[q] = *(const f32x4*)&Wq_l[d2][cb * 32 + q * 4];
        wq1[q] = *(const f32x4*)&Wq_l[d2 + 8][cb * 32 + q * 4];
      }
#pragma unroll
      for (int q = 0; q < 8; ++q) {
#pragma unroll
        for (int cc = 0; cc < 4; ++cc) {
          const int c = cb * 32 + q * 4 + cc;
          const f32x4 sv = *(const f32x4*)&S_l[c][j0];  // S[c][j] == S[j][c]
          aK0 += sv * wk0[q][cc];
          aK1 += sv * wk1[q][cc];
          aQ0 += sv * wq0[q][cc];
          aQ1 += sv * wq1[q][cc];
        }
      }
    }
    *(f32x4*)&Tk_l[d2][j0]     = aK0;
    *(f32x4*)&Tk_l[d2 + 8][j0] = aK1;
    *(f32x4*)&Tq_l[d2][j0]     = aQ0;
    *(f32x4*)&Tq_l[d2 + 8][j0] = aQ1;
  }
  __syncthreads();

  {
    const int d = tid >> 4, e = tid & 15;
    f32x4 gacc = (f32x4){0.f,0.f,0.f,0.f};
    f32x4 kacc = (f32x4){0.f,0.f,0.f,0.f};
    f32x4 qacc = (f32x4){0.f,0.f,0.f,0.f};
#pragma unroll
    for (int j4 = 0; j4 < 32; ++j4) {
      const f32x4 tk = *(const f32x4*)&Tk_l[d][j4 * 4];
      const f32x4 wq = *(const f32x4*)&Wq_l[e][j4 * 4];
      gacc += tk * wq;
      if (e == 0) kacc += tk * (*(const f32x4*)&Wk_l[d][j4 * 4]);
      if (d == 0) qacc += (*(const f32x4*)&Tq_l[e][j4 * 4]) * wq;
    }
    if (e == 0) dK[d] = kacc[0] + kacc[1] + kacc[2] + kacc[3];
    if (d == 0) dQ[e] = qacc[0] + qacc[1] + qacc[2] + qacc[3];
    __syncthreads();
    const float g = gacc[0] + gacc[1] + gacc[2] + gacc[3];
    const float nk = fmaxf(sqrtf(fmaxf(dK[d], 0.f)), 1e-12f);
    const float nq = fmaxf(sqrtf(fmaxf(dQ[e], 0.f)), 1e-12f);
    float pre = g / (nk * nq) * resc[h];
    float mx = pre;
#pragma unroll
    for (int m = 1; m < 16; m <<= 1) mx = fmaxf(mx, __shfl_xor(mx, m, 64));
    const float p = expf(pre - mx);
    float sum = p;
#pragma unroll
    for (int m = 1; m < 16; m <<= 1) sum += __shfl_xor(sum, m, 64);
    attn[blk * 256 + tid] = p / sum;
  }
}

// ---------------------------------------------------------------------------
// D5: k3_p (proven, verbatim) -- Phi = Wp * blockdiag(attn) * Wv, bf16.
// ---------------------------------------------------------------------------
__global__ __launch_bounds__(256) void k3_p(const float* __restrict__ attn,
                                            const float* __restrict__ Wp,
                                            const float* __restrict__ Wv,
                                            bf16_t* __restrict__ Phi) {
  const int blk = blockIdx.x;  // 256 = b*128 + row
  const int b = blk >> 7, rrow = blk & 127;
  const int tid = threadIdx.x;
  __shared__ float M[128];
  if (tid < 128) {
    const int h = tid >> 4, e = tid & 15;
    const float* A = attn + (size_t)(b * 8 + h) * 256;
    const float* wp = Wp + rrow * 128 + h * 16;
    float m = 0.f;
#pragma unroll
    for (int d = 0; d < 16; ++d) m += wp[d] * A[d * 16 + e];
    M[tid] = m;
  }
  __syncthreads();
  if (tid < 128) {
    const int c = tid;
    float p = 0.f;
#pragma unroll 4
    for (int j = 0; j < 128; ++j) p += M[j] * Wv[j * 128 + c];
    Phi[((size_t)b << 14) + rrow * 128 + c] = (bf16_t)p;
  }
}

// ---------------------------------------------------------------------------
// D6: k4_out (R7-proven, verbatim): Phi staged in LDS (pitch 136), X tile
// XOR bank-swizzled, LDS-transposed f32x4 output stores.
// ---------------------------------------------------------------------------
__global__ __launch_bounds__(256) void k4_out(const float* __restrict__ x,
                                              const bf16_t* __restrict__ Phi,
                                              const float* __restrict__ bp,
                                              float* __restrict__ out) {
  const int blk = blockIdx.x;
  const int b = blk / 768, tg = blk % 768;
  const float* Xb = x + (size_t)b * CDIM * NTOK;
  const bf16_t* Ph = Phi + ((size_t)b << 14);
  float* Ob = out + (size_t)b * CDIM * NTOK;
  const int tid = threadIdx.x, wave = tid >> 6, lane = tid & 63;
  const int r = lane & 15, quad = lane >> 4;
  const int tok0 = tg * 64;

  __shared__ __align__(16) char smem[16384 + 34816];  // tile | Phi_l (tbuf aliases Phi_l)
  bf16_t* tile = (bf16_t*)smem;
  bf16_t* Phl = (bf16_t*)(smem + 16384);
  float* tbuf = (float*)(smem + 16384);

  // ---- stage Phi -> LDS (pitch 136) ----
#pragma unroll
  for (int i = 0; i < 8; ++i) {
    const int g = i * 256 + tid;           // 2048 x 16B chunks
    const int prow = g >> 4, pc = g & 15;
    *(bf16x8*)&Phl[prow * 136 + pc * 8] = *(const bf16x8*)(Ph + prow * 128 + pc * 8);
  }

  // ---- stage X tile (fp32 -> bf16, frag order, XOR-swizzled) ----
  {
    const int sch = tid >> 1, shalf = tid & 1;
    const float* p = Xb + (size_t)sch * NTOK + tok0 + shalf * 32;
    f32x4 st[8];
#pragma unroll
    for (int q = 0; q < 8; ++q) st[q] = *(const f32x4*)(p + q * 4);
    const int chunk_hi = ((sch >> 5) << 8) + (((sch >> 3) & 3) << 4);
    const int ei = sch & 7;
#pragma unroll
    for (int j = 0; j < 32; ++j) {
      const int tok = shalf * 32 + j;
      const int chunk = chunk_hi + ((tok >> 4) << 6) + (tok & 15);
      const int sw = chunk ^ ((chunk >> 4) & 3);   // bank-spread involution
      tile[sw * 8 + ei] = (bf16_t)st[j >> 2][j & 3];
    }
  }
  __syncthreads();

  f32x4 acc[8];
#pragma unroll
  for (int m = 0; m < 8; ++m) acc[m] = (f32x4){0.f, 0.f, 0.f, 0.f};

#pragma unroll
  for (int step = 0; step < 4; ++step) {
    const int rc = step * 256 + wave * 64 + lane;
    const bf16x8 bfr = *(const bf16x8*)&tile[(rc ^ ((rc >> 4) & 3)) * 8];
#pragma unroll
    for (int m = 0; m < 8; ++m) {
      const bf16x8 ah = *(const bf16x8*)&Phl[(16 * m + r) * 136 + step * 32 + quad * 8];
      acc[m] = mfma16(ah, bfr, acc[m]);
    }
  }

  __syncthreads();  // MFMA done: tile + Phi_l dead, tbuf reuse safe
#pragma unroll
  for (int half = 0; half < 2; ++half) {
#pragma unroll
    for (int mm = 0; mm < 4; ++mm) {
#pragma unroll
      for (int reg = 0; reg < 4; ++reg)
        tbuf[(mm * 16 + quad * 4 + reg) * 68 + wave * 16 + r] = acc[half * 4 + mm][reg];
    }
    __syncthreads();
#pragma unroll
    for (int rep = 0; rep < 4; ++rep) {
      const int idx = rep * 256 + tid, rloc = idx >> 4, g = idx & 15;
      f32x4 v = *(const f32x4*)&tbuf[rloc * 68 + g * 4];
      const int row = half * 64 + rloc;
      const float bb = bp[row];
      v[0] += bb; v[1] += bb; v[2] += bb; v[3] += bb;
      *(f32x4*)&Ob[(size_t)row * NTOK + tok0 + g * 4] = v;
    }
    if (half == 0) __syncthreads();
  }
}

extern "C" void kernel_launch(void* const* d_in, const int* in_sizes, int n_in,
                              void* d_out, int out_size, void* d_ws, size_t ws_size,
                              hipStream_t stream) {
  const float* x    = (const float*)d_in[0];
  const float* Wq   = (const float*)d_in[1];
  const float* Wk   = (const float*)d_in[2];
  const float* Wv   = (const float*)d_in[3];
  const float* Wp   = (const float*)d_in[4];
  const float* bp   = (const float*)d_in[5];
  const float* resc = (const float*)d_in[6];
  float* out = (float*)d_out;

  // ws layout: S f32[2*128*128] @0 (131072 B) | attn f32[2*8*256] @131072
  // (16384 B) | Phi bf16[2*128*128] @147456 (65536 B).
  char* ws = (char*)d_ws;
  float*  S    = (float*)(ws + 0);
  float*  attn = (float*)(ws + 131072);
  bf16_t* Phi  = (bf16_t*)(ws + 147456);
  // Big scratch inside d_out (50.3 MB): part 16 MB + part2 1 MB at +16 MB,
  // consumed (k2a/k2b) before k4 overwrites d_out with the real output.
  float* part  = (float*)d_out;
  float* part2 = (float*)((char*)d_out + 16777216);

  k1_gram<<<2 * CHUNKS, 512, 0, stream>>>(x, part);
  k2a_reduce<<<256, 256, 0, stream>>>(part, part2);
  k2b_reduce<<<32, 256, 0, stream>>>(part2, S);
  kattn<<<16, 256, 0, stream>>>(S, Wk, Wq, resc, attn);
  k3_p<<<256, 256, 0, stream>>>(attn, Wp, Wv, Phi);
  k4_out<<<1536, 256, 0, stream>>>(x, Phi, bp, out);
}